// Round 9
// baseline (1839.561 us; speedup 1.0000x reference)
//
#include <hip/hip_runtime.h>
#include <stdint.h>

// ---------------- problem constants ----------------
#define T_TOK   8192          // B*S
#define D_DIM   1024
#define FF_DIM  4096
#define E_NUM   8
#define SLOT_MAX 18432        // 16384 + 8*256 (worst-case 256-padded slots)
#define RT_MAX  104           // 72 moe row-tiles + 32 dense row-tiles (256-row tiles)

typedef unsigned int   u32;
typedef unsigned short u16;
typedef __attribute__((ext_vector_type(4))) float  f32x4;
typedef __attribute__((ext_vector_type(4))) float  f4;
typedef __attribute__((ext_vector_type(8))) short  bf16x8;   // 8 bf16 = 4 VGPR
typedef __attribute__((ext_vector_type(8))) unsigned short u16x8;
typedef __attribute__((ext_vector_type(4))) unsigned short u16x4;

__device__ __forceinline__ u16 f2bf(float f) {              // RNE f32->bf16
  u32 u = __builtin_bit_cast(u32, f);
  return (u16)((u + 0x7fffu + ((u >> 16) & 1u)) >> 16);
}
__device__ __forceinline__ float bf2f(u16 h) {
  u32 u = ((u32)h) << 16; return __builtin_bit_cast(float, u);
}

typedef const __attribute__((address_space(1))) u32* gp1_t;
typedef __attribute__((address_space(3))) u32*       lp3_t;
__device__ __forceinline__ void gload16(const u16* g, u16* l) {
  // async global->LDS, 16B/lane, LDS dest = wave-uniform base + lane*16 (linear)
  __builtin_amdgcn_global_load_lds((gp1_t)(const void*)g, (lp3_t)l, 16, 0, 0);
}

// ---------- K1: router + gate (wave per token, 4 d/lane) + fused x->bf16 ----------
__global__ __launch_bounds__(256) void k_route(
    const float* __restrict__ x, const float* __restrict__ Wr, const float* __restrict__ br,
    const float* __restrict__ Wg, const float* __restrict__ bg,
    int* __restrict__ hdr, int4* __restrict__ tok_sel, float4* __restrict__ tok_wf,
    u16* __restrict__ xb)
{
  int w = threadIdx.x >> 6, l = threadIdx.x & 63;
  int t = blockIdx.x * 4 + w;
  const float* xt = x + (size_t)t * D_DIM;
  u16* xbt = xb + (size_t)t * D_DIM;
  float p[10];
  #pragma unroll
  for (int i = 0; i < 10; ++i) p[i] = 0.f;
  #pragma unroll
  for (int j = 0; j < 4; ++j) {
    int d0 = j * 256 + l * 4;
    f4 xv = *(const f4*)&xt[d0];
    u16x4 xo; xo[0]=f2bf(xv[0]); xo[1]=f2bf(xv[1]); xo[2]=f2bf(xv[2]); xo[3]=f2bf(xv[3]);
    *(u16x4*)&xbt[d0] = xo;
    f4 wra = *(const f4*)&Wr[d0 * 2];
    f4 wrb = *(const f4*)&Wr[d0 * 2 + 4];
    p[0] += xv[0]*wra[0] + xv[1]*wra[2] + xv[2]*wrb[0] + xv[3]*wrb[2];
    p[1] += xv[0]*wra[1] + xv[1]*wra[3] + xv[2]*wrb[1] + xv[3]*wrb[3];
    #pragma unroll
    for (int i = 0; i < 4; ++i) {
      f4 g0 = *(const f4*)&Wg[(size_t)(d0 + i) * 8];
      f4 g1 = *(const f4*)&Wg[(size_t)(d0 + i) * 8 + 4];
      p[2] += xv[i]*g0[0]; p[3] += xv[i]*g0[1]; p[4] += xv[i]*g0[2]; p[5] += xv[i]*g0[3];
      p[6] += xv[i]*g1[0]; p[7] += xv[i]*g1[1]; p[8] += xv[i]*g1[2]; p[9] += xv[i]*g1[3];
    }
  }
  #pragma unroll
  for (int off = 32; off; off >>= 1) {
    #pragma unroll
    for (int i = 0; i < 10; ++i) p[i] += __shfl_xor(p[i], off, 64);
  }
  if (l == 0) {
    float a0 = p[0] + br[0], a1 = p[1] + br[1];
    float m  = fmaxf(a0, a1);
    float e0 = __expf(a0 - m), e1 = __expf(a1 - m);
    float rs = 1.f / (e0 + e1);
    float rp0 = e0 * rs, rp1 = e1 * rs;
    float g[E_NUM]; float gm = -1e30f;
    #pragma unroll
    for (int e = 0; e < E_NUM; ++e) { g[e] = p[2 + e] + bg[e]; gm = fmaxf(gm, g[e]); }
    int i0 = 0;
    #pragma unroll
    for (int e = 1; e < E_NUM; ++e) if (g[e] > g[i0]) i0 = e;      // earliest max tiebreak
    int i1 = (i0 == 0) ? 1 : 0;
    #pragma unroll
    for (int e = 0; e < E_NUM; ++e) if (e != i0 && g[e] > g[i1]) i1 = e;
    float x0 = __expf(g[i0] - gm), x1 = __expf(g[i1] - gm);
    float s = 1.f / (x0 + x1);
    int r0 = atomicAdd(&hdr[i0], 1);
    int r1 = atomicAdd(&hdr[i1], 1);
    tok_sel[t] = make_int4(i0, r0, i1, r1);
    tok_wf[t]  = make_float4(x0 * s, x1 * s, rp0, rp1);
  }
}

// ---- K2: setup (offsets + tilemap + perm init + scatter), single block ----
__global__ __launch_bounds__(256) void k_setup(
    int* __restrict__ hdr, int4* __restrict__ tilemap, int* __restrict__ perm,
    const int4* __restrict__ tok_sel, int2* __restrict__ tok_slot)
{
  __shared__ int soff[E_NUM + 1];
  int tid = threadIdx.x;
  if (tid == 0) {
    int acc = 0;
    for (int e = 0; e < E_NUM; ++e) {
      soff[e] = acc; hdr[8 + e] = acc;
      acc += (hdr[e] + 255) & ~255;                // pad each expert to 256
    }
    soff[E_NUM] = acc;
    hdr[16] = acc;                                 // nslots_padded
    hdr[17] = acc >> 8;                            // moe row-tiles (256-row)
    hdr[18] = (acc >> 8) + T_TOK / 256;            // total row-tiles
  }
  __syncthreads();
  int nmoe = soff[E_NUM] >> 8;
  for (int rt = tid; rt < RT_MAX; rt += 256) {
    int4 ent;
    if (rt < nmoe) {
      int row0 = rt * 256;
      int e = 0;
      while (e < E_NUM - 1 && row0 >= soff[e + 1]) ++e;
      ent = make_int4(0, row0, e, 0);
    } else if (rt < nmoe + T_TOK / 256) {
      ent = make_int4(1, (rt - nmoe) * 256, -1, 0);
    } else {
      ent = make_int4(-1, 0, 0, 0);
    }
    tilemap[rt] = ent;
  }
  for (int s = tid; s < SLOT_MAX; s += 256) perm[s] = -1;
  __syncthreads();
  for (int t = tid; t < T_TOK; t += 256) {
    int4 s = tok_sel[t];
    int s0 = soff[s.x] + s.y;
    int s1 = soff[s.z] + s.w;
    perm[s0] = t; perm[s1] = t;
    tok_slot[t] = make_int2(s0, s1);
  }
}

// -- K6: fused cast+transpose f32 [R,C] -> bf16 [C,R], 128x64 tiles, 18 panels --
__global__ __launch_bounds__(256) void k_tcast_all(
    const float* __restrict__ W1, const float* __restrict__ W2,
    const float* __restrict__ D1, const float* __restrict__ D2,
    u16* __restrict__ W1bt, u16* __restrict__ W2bt,
    u16* __restrict__ D1bt, u16* __restrict__ D2bt)
{
  int bid = blockIdx.x;
  int panel = bid >> 9, pb = bid & 511;
  const float* s; u16* d; int R, C, ltc;
  if (panel < 8)       { s = W1 + (size_t)panel * D_DIM * FF_DIM; d = W1bt + (size_t)panel * D_DIM * FF_DIM; R = D_DIM;  C = FF_DIM; ltc = 6; }
  else if (panel < 16) { int e = panel - 8;
                         s = W2 + (size_t)e * FF_DIM * D_DIM;     d = W2bt + (size_t)e * FF_DIM * D_DIM;     R = FF_DIM; C = D_DIM;  ltc = 4; }
  else if (panel == 16){ s = D1; d = D1bt; R = D_DIM;  C = FF_DIM; ltc = 6; }
  else                 { s = D2; d = D2bt; R = FF_DIM; C = D_DIM;  ltc = 4; }
  int tc = pb & ((1 << ltc) - 1), tr = pb >> ltc;    // tr: 128-row tile, tc: 64-col tile

  __shared__ float tile[128][65];
  int t = threadIdx.x;
  #pragma unroll
  for (int p = 0; p < 8; ++p) {
    int r = p * 16 + (t >> 4);
    int c4 = (t & 15) * 4;
    f4 v = *(const f4*)&s[(size_t)(tr * 128 + r) * C + tc * 64 + c4];
    tile[r][c4+0] = v[0]; tile[r][c4+1] = v[1]; tile[r][c4+2] = v[2]; tile[r][c4+3] = v[3];
  }
  __syncthreads();
  #pragma unroll
  for (int q = 0; q < 4; ++q) {
    int oc = q * 16 + (t >> 4);
    int r8 = (t & 15) * 8;
    u16x8 o;
    #pragma unroll
    for (int j = 0; j < 8; ++j) o[j] = f2bf(tile[r8 + j][oc]);
    *(u16x8*)&d[(size_t)(tc * 64 + oc) * R + tr * 128 + r8] = o;
  }
}

// ---- K7/K8: grouped GEMM, 8-phase/2-tile serpentine pipeline, BM=BN=256 ----
// Same 2-barrier-per-phase skeleton as r4/r6 (verified), but reads issued ONE
// phase ahead with COUNTED lgkmcnt (T4): serpentine quadrant order makes every
// operand's re-read >=1 phase after last use -> single register sets, no WAR.
// Per pair (tiles t@buf0, t+1@buf1), phases:
//  ph0: rd b1(t);          st Ah1(t+1)@b1;              lgkm4;  MFMA(a0,b0->0,0)
//  ph1: vm8; rd a1(t);                                  lgkm8;  MFMA(a0,b1->0,2)
//  ph2: vm2; rd a0(t+1);   st Bh0(t+2)@b0;              lgkm8;  MFMA(a1,b1->4,2)
//  ph3: rd b1(t+1);        st Bh1(t+2)+Ah0(t+2)@b0;     --   ;  MFMA(a1,b0->4,0)
//  ph4: rd b0(t+1);        st Ah1(t+2)@b0;              lgkm4;  MFMA(a0,b1->0,2)
//  ph5: vm8; rd a1(t+1);                                lgkm8;  MFMA(a0,b0->0,0)
//  ph6: vm2; rd a0(t+2);   st Bh0(t+3)@b1;              lgkm8;  MFMA(a1,b0->4,0)
//  ph7: rd b0(t+2);        st Bh1(t+3)+Ah0(t+3)@b1;     --   ;  MFMA(a1,b1->4,2)
// lgkm counts = reads allowed outstanding (in-order retirement); vmcnt ledger
// verified incl. prologue (tile0 full + Bh0/Bh1/Ah0(1); vm6; pre-read a0,b0(0))
// and LAST pair (vm0@ph5, lgkm0@ph6, stages/reads of t+2,t+3 skipped).
#define VMW(n)  asm volatile("s_waitcnt vmcnt(" #n ")" ::: "memory")
#define LGKM(n) { asm volatile("s_waitcnt lgkmcnt(" #n ")" ::: "memory"); \
                  __builtin_amdgcn_sched_barrier(0); }
#define SB()    __builtin_amdgcn_sched_barrier(0)
#define BAR()   __builtin_amdgcn_s_barrier()

template <int RELU, int GATHER>
__global__ __launch_bounds__(512, 2) void k_gemm8p(
    const u16* __restrict__ Amoe, const u16* __restrict__ Aden,
    const u16* __restrict__ Bexp, const u16* __restrict__ Bden,
    const float* __restrict__ biasexp, const float* __restrict__ biasden,
    u16* __restrict__ Omoe, u16* __restrict__ Oden,
    const int* __restrict__ hdr, const int4* __restrict__ tilemap,
    const int* __restrict__ perm,
    int K, int N, long bexp_stride, int biasexp_stride, int lg2gx)
{
  // bijective XCD-aware swizzle (nwg % 8 == 0 for both launches)
  int gx  = 1 << lg2gx;
  int nwg = gx * gridDim.y;
  int lin = blockIdx.y * gx + blockIdx.x;
  int sw  = (lin & 7) * (nwg >> 3) + (lin >> 3);
  int ct  = sw & (gx - 1);
  int rt  = sw >> lg2gx;
  if (rt >= hdr[18]) return;

  int4 ent = tilemap[rt];
  const u16* B; const float* bias; u16* O;
  if (ent.x == 1) { B = Bden; bias = biasden; O = Oden; }
  else {
    B = Bexp + (size_t)ent.z * bexp_stride;
    bias = biasexp + (size_t)ent.z * biasexp_stride;
    O = Omoe;
  }
  const int row0 = ent.y;

  __shared__ __align__(16) u16 lds[65536];     // 128KB

  const int tid = threadIdx.x;
  const int wid = tid >> 6, l = tid & 63;
  const int wm = wid >> 2, wn = wid & 3;

  // --- staging sources: 4 precomputed row pointers each for A and B ---
  const int srow = wid * 8 + (l >> 3);
  const int skel = ((l & 7) ^ (l >> 3)) * 8;            // swizzled k-elem in [0,64)
  const u16* aSrcP[4];
  const u16* bSrcP[4];
  #pragma unroll
  for (int i = 0; i < 4; ++i) {
    int r = srow + i * 64;
    if (ent.x == 1)      aSrcP[i] = Aden + (size_t)(row0 + r) * K + skel;
    else if (GATHER) {
      int pr = perm[row0 + r]; pr = pr < 0 ? 0 : pr;     // clamp pads to token 0
      aSrcP[i] = Amoe + (size_t)pr * K + skel;
    } else               aSrcP[i] = Amoe + (size_t)(row0 + r) * K + skel;
    bSrcP[i] = B + (size_t)(ct * 256 + r) * K + skel;
  }

  // --- frag-read base pointers; all reads = base + compile-time immediate ---
  const int fr = l & 15, fq = l >> 4;
  const int fx = (l & 7) << 4;                           // row&7 == l&7 for frag rows
  const int cs0 = (fq * 16) ^ fx;
  const int cs1 = (64 + fq * 16) ^ fx;                   // == cs0 ^ 64
  const int brow = (wn & 1) * 64;
  const char* ldsc = (const char*)lds;
  const char* aP0 = ldsc + wm * 16384 + fr * 128 + cs0;
  const char* aP1 = ldsc + wm * 16384 + fr * 128 + cs1;
  const char* bP0 = ldsc + 65536 + (wn >> 1) * 16384 + (brow + fr) * 128 + cs0;
  const char* bP1 = ldsc + 65536 + (wn >> 1) * 16384 + (brow + fr) * 128 + cs1;

  auto STAGE_A = [&](int tt, int h, int bb) {
    u16* dst = &lds[(bb * 2 + h) * 8192 + wid * 512];
    gload16(aSrcP[h * 2]     + tt * 64, dst);
    gload16(aSrcP[h * 2 + 1] + tt * 64, dst + 4096);
  };
  auto STAGE_B = [&](int tt, int h, int bb) {
    u16* dst = &lds[32768 + (bb * 2 + h) * 8192 + wid * 512];
    gload16(bSrcP[h * 2]     + tt * 64, dst);
    gload16(bSrcP[h * 2 + 1] + tt * 64, dst + 4096);
  };

  f32x4 acc[8][4];
  #pragma unroll
  for (int m = 0; m < 8; ++m)
    #pragma unroll
    for (int n = 0; n < 4; ++n) acc[m][n] = (f32x4){0.f, 0.f, 0.f, 0.f};

  bf16x8 a0[4][2], a1[4][2], b0[2][2], b1[2][2];

  #define READ_A0(B_) { _Pragma("unroll") for (int j = 0; j < 4; ++j) { \
      a0[j][0] = *(const bf16x8*)(aP0 + ((B_)*32768 + j*2048)); \
      a0[j][1] = *(const bf16x8*)(aP1 + ((B_)*32768 + j*2048)); } }
  #define READ_A1(B_) { _Pragma("unroll") for (int j = 0; j < 4; ++j) { \
      a1[j][0] = *(const bf16x8*)(aP0 + ((B_)*32768 + 8192 + j*2048)); \
      a1[j][1] = *(const bf16x8*)(aP1 + ((B_)*32768 + 8192 + j*2048)); } }
  #define READ_B0(B_) { _Pragma("unroll") for (int i = 0; i < 2; ++i) { \
      b0[i][0] = *(const bf16x8*)(bP0 + ((B_)*32768 + i*2048)); \
      b0[i][1] = *(const bf16x8*)(bP1 + ((B_)*32768 + i*2048)); } }
  #define READ_B1(B_) { _Pragma("unroll") for (int i = 0; i < 2; ++i) { \
      b1[i][0] = *(const bf16x8*)(bP0 + ((B_)*32768 + 4096 + i*2048)); \
      b1[i][1] = *(const bf16x8*)(bP1 + ((B_)*32768 + 4096 + i*2048)); } }
  #define MFMA_Q(am, bm, mo, no) { __builtin_amdgcn_s_setprio(1); \
    _Pragma("unroll") for (int j = 0; j < 4; ++j) \
      _Pragma("unroll") for (int i = 0; i < 2; ++i) { \
        acc[(mo) + j][(no) + i] = __builtin_amdgcn_mfma_f32_16x16x32_bf16(am[j][0], bm[i][0], acc[(mo) + j][(no) + i], 0, 0, 0); \
        acc[(mo) + j][(no) + i] = __builtin_amdgcn_mfma_f32_16x16x32_bf16(am[j][1], bm[i][1], acc[(mo) + j][(no) + i], 0, 0, 0); } \
    __builtin_amdgcn_s_setprio(0); }

  const int NK = K >> 6;                                 // 16 or 64 (even, >=4)

  // prologue: tile0 full (8 loads) + Bh0(1),Bh1(1),Ah0(1) (6 loads);
  // vmcnt(6) certifies tile0; pre-issue ds_reads a0(0),b0(0).
  STAGE_B(0, 0, 0); STAGE_B(0, 1, 0); STAGE_A(0, 0, 0); STAGE_A(0, 1, 0);
  STAGE_B(1, 0, 1); STAGE_B(1, 1, 1); STAGE_A(1, 0, 1);
  VMW(6);
  BAR();
  READ_A0(0); READ_B0(0);
  SB();

  #define PAIR(t_, LAST_) { \
    /* ph0 */ \
    READ_B1(0); \
    STAGE_A((t_) + 1, 1, 1); \
    SB(); BAR(); LGKM(4); \
    MFMA_Q(a0, b0, 0, 0); BAR(); \
    /* ph1 */ \
    VMW(8); READ_A1(0); SB(); BAR(); LGKM(8); \
    MFMA_Q(a0, b1, 0, 2); BAR(); \
    /* ph2 */ \
    VMW(2); READ_A0(1); \
    if (!(LAST_)) STAGE_B((t_) + 2, 0, 0); \
    SB(); BAR(); LGKM(8); \
    MFMA_Q(a1, b1, 4, 2); BAR(); \
    /* ph3 */ \
    READ_B1(1); \
    if (!(LAST_)) { STAGE_B((t_) + 2, 1, 0); STAGE_A((t_) + 2, 0, 0); } \
    SB(); BAR(); \
    MFMA_Q(a1, b0, 4, 0); BAR(); \
    /* ph4 */ \
    READ_B0(1); \
    if (!(LAST_)) STAGE_A((t_) + 2, 1, 0); \
    SB(); BAR(); LGKM(4); \
    MFMA_Q(a0, b1, 0, 2); BAR(); \
    /* ph5 */ \
    if (LAST_) { VMW(0); } else { VMW(8); } \
    READ_A1(1); SB(); BAR(); LGKM(8); \
    MFMA_Q(a0, b0, 0, 0); BAR(); \
    /* ph6 */ \
    if (!(LAST_)) { VMW(2); READ_A0(0); STAGE_B((t_) + 3, 0, 1); } \
    SB(); BAR(); \
    if (LAST_) { LGKM(0); } else { LGKM(8); } \
    MFMA_Q(a1, b0, 4, 0); BAR(); \
    /* ph7 */ \
    if (!(LAST_)) { READ_B0(0); STAGE_B((t_) + 3, 1, 1); STAGE_A((t_) + 3, 0, 1); } \
    SB(); BAR(); \
    MFMA_Q(a1, b1, 4, 2); BAR(); \
  }

  for (int t = 0; t + 2 < NK; t += 2) PAIR(t, 0);
  PAIR(NK - 2, 1);
  #undef PAIR

  // ---- epilogue: per-wave padded LDS-bounce transpose -> u16x8 stores ----
  __syncthreads();
  float bv[4];
  #pragma unroll
  for (int ni = 0; ni < 4; ++ni) bv[ni] = bias[ct * 256 + wn * 64 + ni * 16 + fr];
  float* ep = (float*)((char*)lds + wid * 4608);         // 16 x 68 floats, padded
  const int row16 = l >> 2, cg = l & 3;
  #pragma unroll
  for (int mi = 0; mi < 8; ++mi) {
    #pragma unroll
    for (int ni = 0; ni < 4; ++ni) {
      f32x4 v = acc[mi][ni];
      #pragma unroll
      for (int j = 0; j < 4; ++j) {
        float f = v[j] + bv[ni];
        if (RELU) f = fmaxf(f, 0.f);
        ep[(fq * 4 + j) * 68 + ni * 16 + fr] = f;        // stride 68: 2-way max
      }
    }
    #pragma unroll
    for (int p = 0; p < 2; ++p) {
      f4 r0 = *(f4*)&ep[row16 * 68 + (cg + p * 4) * 8];
      f4 r1 = *(f4*)&ep[row16 * 68 + (cg + p * 4) * 8 + 4];
      u16x8 o;
      o[0]=f2bf(r0[0]); o[1]=f2bf(r0[1]); o[2]=f2bf(r0[2]); o[3]=f2bf(r0[3]);
      o[4]=f2bf(r1[0]); o[5]=f2bf(r1[1]); o[6]=f2bf(r1[2]); o[7]=f2bf(r1[3]);
      int rr = row0 + wm * 128 + mi * 16 + row16;
      int cc = ct * 256 + wn * 64 + (cg + p * 4) * 8;
      *(u16x8*)&O[(size_t)rr * N + cc] = o;
    }
  }
  #undef READ_A0
  #undef READ_A1
  #undef READ_B0
  #undef READ_B1
  #undef MFMA_Q
}

// ---------------- K9: combine ----------------
__global__ __launch_bounds__(128) void k_combine(
    const u16* __restrict__ eo, const u16* __restrict__ dense_o,
    const float4* __restrict__ tok_wf, const int2* __restrict__ tok_slot,
    float* __restrict__ out)
{
  int t = blockIdx.x;
  int c8 = threadIdx.x;
  float4 wf = tok_wf[t];
  int2 sl = tok_slot[t];
  u16x8 a  = *((const u16x8*)(eo + (size_t)sl.x * D_DIM) + c8);
  u16x8 b  = *((const u16x8*)(eo + (size_t)sl.y * D_DIM) + c8);
  u16x8 dn = *((const u16x8*)(dense_o + (size_t)t * D_DIM) + c8);
  float* op = out + (size_t)t * D_DIM + c8 * 8;
  #pragma unroll
  for (int j = 0; j < 8; ++j) {
    float mo = wf.x * bf2f(a[j]) + wf.y * bf2f(b[j]);
    op[j] = wf.z * mo + wf.w * bf2f(dn[j]);
  }
}

// ---------------- launch ----------------
extern "C" void kernel_launch(void* const* d_in, const int* in_sizes, int n_in,
                              void* d_out, int out_size, void* d_ws, size_t ws_size,
                              hipStream_t stream)
{
  const float* x   = (const float*)d_in[0];
  const float* Wr  = (const float*)d_in[1];
  const float* br  = (const float*)d_in[2];
  const float* Wg  = (const float*)d_in[3];
  const float* bg  = (const float*)d_in[4];
  const float* W1  = (const float*)d_in[5];
  const float* b1  = (const float*)d_in[6];
  const float* W2  = (const float*)d_in[7];
  const float* b2  = (const float*)d_in[8];
  const float* D1  = (const float*)d_in[9];
  const float* d1b = (const float*)d_in[10];
  const float* D2  = (const float*)d_in[11];
  const float* d2b = (const float*)d_in[12];
  float* out = (float*)d_out;

  char* base = (char*)d_ws;
  size_t cur = 0;
  auto alloc = [&](size_t b) -> void* {
    void* p = base + cur; cur = (cur + b + 255) & ~(size_t)255; return p;
  };
  int*    hdr      = (int*)   alloc(256 * sizeof(int));
  int4*   tilemap  = (int4*)  alloc((size_t)RT_MAX * sizeof(int4));
  int4*   tok_sel  = (int4*)  alloc((size_t)T_TOK * sizeof(int4));
  float4* tok_wf   = (float4*)alloc((size_t)T_TOK * sizeof(float4));
  int2*   tok_slot = (int2*)  alloc((size_t)T_TOK * sizeof(int2));
  int*    perm     = (int*)   alloc((size_t)SLOT_MAX * sizeof(int));
  u16*    xb       = (u16*)   alloc((size_t)T_TOK * D_DIM * 2);
  u16*    W1bt     = (u16*)   alloc((size_t)E_NUM * D_DIM * FF_DIM * 2);
  u16*    W2bt     = (u16*)   alloc((size_t)E_NUM * D_DIM * FF_DIM * 2);
  u16*    D1bt     = (u16*)   alloc((size_t)D_DIM * FF_DIM * 2);
  u16*    D2bt     = (u16*)   alloc((size_t)D_DIM * FF_DIM * 2);
  u16*    h_moe    = (u16*)   alloc((size_t)SLOT_MAX * FF_DIM * 2);
  u16*    h_dense  = (u16*)   alloc((size_t)T_TOK * FF_DIM * 2);
  u16*    eo       = (u16*)   alloc((size_t)SLOT_MAX * D_DIM * 2);
  u16*    dense_o  = (u16*)   alloc((size_t)T_TOK * D_DIM * 2);
  (void)in_sizes; (void)n_in; (void)out_size; (void)ws_size; // needs ~440 MB of ws

  hipMemsetAsync(hdr, 0, 256 * sizeof(int), stream);
  k_route    <<<T_TOK / 4, 256, 0, stream>>>(x, Wr, br, Wg, bg, hdr, tok_sel, tok_wf, xb);
  k_setup    <<<1, 256, 0, stream>>>(hdr, tilemap, perm, tok_sel, tok_slot);
  k_tcast_all<<<18 * 512, 256, 0, stream>>>(W1, W2, D1, D2, W1bt, W2bt, D1bt, D2bt);

  // GEMM1: gathered tokens x W1 -> relu -> h   (grid 16x104, K=1024, NK=16)
  k_gemm8p<1, 1><<<dim3(FF_DIM / 256, RT_MAX), 512, 0, stream>>>(
      xb, xb, W1bt, D1bt, b1, d1b, h_moe, h_dense, hdr, tilemap, perm,
      D_DIM, FF_DIM, (long)D_DIM * FF_DIM, FF_DIM, 4);
  // GEMM2: h x W2 -> eo   (grid 4x104, K=4096, NK=64)
  k_gemm8p<0, 0><<<dim3(D_DIM / 256, RT_MAX), 512, 0, stream>>>(
      h_moe, h_dense, W2bt, D2bt, b2, d2b, eo, dense_o, hdr, tilemap, perm,
      FF_DIM, D_DIM, (long)D_DIM * FF_DIM, D_DIM, 2);

  k_combine<<<T_TOK, 128, 0, stream>>>(eo, dense_o, tok_wf, tok_slot, out);
}

// Round 10
// 757.912 us; speedup vs baseline: 2.4271x; 2.4271x over previous
//
#include <hip/hip_runtime.h>
#include <stdint.h>

// ---------------- problem constants ----------------
#define T_TOK   8192          // B*S
#define D_DIM   1024
#define FF_DIM  4096
#define E_NUM   8
#define SLOT_MAX 18432        // 16384 + 8*256 (worst-case 256-padded slots)
#define RT_MAX  104           // 72 moe row-tiles + 32 dense row-tiles (256-row tiles)

typedef unsigned int   u32;
typedef unsigned short u16;
typedef __attribute__((ext_vector_type(4))) float  f32x4;
typedef __attribute__((ext_vector_type(4))) float  f4;
typedef __attribute__((ext_vector_type(8))) short  bf16x8;   // 8 bf16 = 4 VGPR
typedef __attribute__((ext_vector_type(8))) unsigned short u16x8;
typedef __attribute__((ext_vector_type(4))) unsigned short u16x4;

__device__ __forceinline__ u16 f2bf(float f) {              // RNE f32->bf16
  u32 u = __builtin_bit_cast(u32, f);
  return (u16)((u + 0x7fffu + ((u >> 16) & 1u)) >> 16);
}
__device__ __forceinline__ float bf2f(u16 h) {
  u32 u = ((u32)h) << 16; return __builtin_bit_cast(float, u);
}

typedef const __attribute__((address_space(1))) u32* gp1_t;
typedef __attribute__((address_space(3))) u32*       lp3_t;
__device__ __forceinline__ void gload16(const u16* g, u16* l) {
  // async global->LDS, 16B/lane, LDS dest = wave-uniform base + lane*16 (linear)
  __builtin_amdgcn_global_load_lds((gp1_t)(const void*)g, (lp3_t)l, 16, 0, 0);
}

// ---------- K1: router + gate (wave per token, 4 d/lane) + fused x->bf16 ----------
__global__ __launch_bounds__(256) void k_route(
    const float* __restrict__ x, const float* __restrict__ Wr, const float* __restrict__ br,
    const float* __restrict__ Wg, const float* __restrict__ bg,
    int* __restrict__ hdr, int4* __restrict__ tok_sel, float4* __restrict__ tok_wf,
    u16* __restrict__ xb)
{
  int w = threadIdx.x >> 6, l = threadIdx.x & 63;
  int t = blockIdx.x * 4 + w;
  const float* xt = x + (size_t)t * D_DIM;
  u16* xbt = xb + (size_t)t * D_DIM;
  float p[10];
  #pragma unroll
  for (int i = 0; i < 10; ++i) p[i] = 0.f;
  #pragma unroll
  for (int j = 0; j < 4; ++j) {
    int d0 = j * 256 + l * 4;
    f4 xv = *(const f4*)&xt[d0];
    u16x4 xo; xo[0]=f2bf(xv[0]); xo[1]=f2bf(xv[1]); xo[2]=f2bf(xv[2]); xo[3]=f2bf(xv[3]);
    *(u16x4*)&xbt[d0] = xo;
    f4 wra = *(const f4*)&Wr[d0 * 2];
    f4 wrb = *(const f4*)&Wr[d0 * 2 + 4];
    p[0] += xv[0]*wra[0] + xv[1]*wra[2] + xv[2]*wrb[0] + xv[3]*wrb[2];
    p[1] += xv[0]*wra[1] + xv[1]*wra[3] + xv[2]*wrb[1] + xv[3]*wrb[3];
    #pragma unroll
    for (int i = 0; i < 4; ++i) {
      f4 g0 = *(const f4*)&Wg[(size_t)(d0 + i) * 8];
      f4 g1 = *(const f4*)&Wg[(size_t)(d0 + i) * 8 + 4];
      p[2] += xv[i]*g0[0]; p[3] += xv[i]*g0[1]; p[4] += xv[i]*g0[2]; p[5] += xv[i]*g0[3];
      p[6] += xv[i]*g1[0]; p[7] += xv[i]*g1[1]; p[8] += xv[i]*g1[2]; p[9] += xv[i]*g1[3];
    }
  }
  #pragma unroll
  for (int off = 32; off; off >>= 1) {
    #pragma unroll
    for (int i = 0; i < 10; ++i) p[i] += __shfl_xor(p[i], off, 64);
  }
  if (l == 0) {
    float a0 = p[0] + br[0], a1 = p[1] + br[1];
    float m  = fmaxf(a0, a1);
    float e0 = __expf(a0 - m), e1 = __expf(a1 - m);
    float rs = 1.f / (e0 + e1);
    float rp0 = e0 * rs, rp1 = e1 * rs;
    float g[E_NUM]; float gm = -1e30f;
    #pragma unroll
    for (int e = 0; e < E_NUM; ++e) { g[e] = p[2 + e] + bg[e]; gm = fmaxf(gm, g[e]); }
    int i0 = 0;
    #pragma unroll
    for (int e = 1; e < E_NUM; ++e) if (g[e] > g[i0]) i0 = e;      // earliest max tiebreak
    int i1 = (i0 == 0) ? 1 : 0;
    #pragma unroll
    for (int e = 0; e < E_NUM; ++e) if (e != i0 && g[e] > g[i1]) i1 = e;
    float x0 = __expf(g[i0] - gm), x1 = __expf(g[i1] - gm);
    float s = 1.f / (x0 + x1);
    int r0 = atomicAdd(&hdr[i0], 1);
    int r1 = atomicAdd(&hdr[i1], 1);
    tok_sel[t] = make_int4(i0, r0, i1, r1);
    tok_wf[t]  = make_float4(x0 * s, x1 * s, rp0, rp1);
  }
}

// ---- K2: setup (offsets + tilemap + pad-init + scatter), 32 blocks ----
// Every block recomputes soff from hdr[0..7]; writes are disjoint:
// tilemap grid-strided, perm init ONLY over pad ranges (never scattered),
// scatter over tokens. No init-then-overwrite race.
__global__ __launch_bounds__(256) void k_setup(
    int* __restrict__ hdr, int4* __restrict__ tilemap, int* __restrict__ perm,
    const int4* __restrict__ tok_sel, int2* __restrict__ tok_slot)
{
  int soff[E_NUM + 1], cnt[E_NUM];
  int acc = 0;
  #pragma unroll
  for (int e = 0; e < E_NUM; ++e) {
    cnt[e] = hdr[e];
    soff[e] = acc;
    acc += (cnt[e] + 255) & ~255;                // pad each expert to 256
  }
  soff[E_NUM] = acc;
  const int gtid = blockIdx.x * 256 + threadIdx.x;
  const int nthr = gridDim.x * 256;
  if (gtid == 0) {
    #pragma unroll
    for (int e = 0; e < E_NUM; ++e) hdr[8 + e] = soff[e];
    hdr[16] = acc;                               // nslots_padded
    hdr[17] = acc >> 8;                          // moe row-tiles (256-row)
    hdr[18] = (acc >> 8) + T_TOK / 256;          // total row-tiles
  }
  int nmoe = acc >> 8;
  for (int rt = gtid; rt < RT_MAX; rt += nthr) {
    int4 ent;
    if (rt < nmoe) {
      int row0 = rt * 256;
      int e = 0;
      while (e < E_NUM - 1 && row0 >= soff[e + 1]) ++e;
      ent = make_int4(0, row0, e, 0);
    } else if (rt < nmoe + T_TOK / 256) {
      ent = make_int4(1, (rt - nmoe) * 256, -1, 0);
    } else {
      ent = make_int4(-1, 0, 0, 0);
    }
    tilemap[rt] = ent;
  }
  #pragma unroll
  for (int e = 0; e < E_NUM; ++e) {              // init pad slots only
    int lo = soff[e] + cnt[e];
    int hi = soff[e + 1];
    for (int s = lo + gtid; s < hi; s += nthr) perm[s] = -1;
  }
  for (int t = gtid; t < T_TOK; t += nthr) {
    int4 s = tok_sel[t];
    int s0 = soff[s.x] + s.y;
    int s1 = soff[s.z] + s.w;
    perm[s0] = t; perm[s1] = t;
    tok_slot[t] = make_int2(s0, s1);
  }
}

// -- K6: fused cast+transpose f32 [R,C] -> bf16 [C,R], 128x64 tiles, 18 panels --
__global__ __launch_bounds__(256) void k_tcast_all(
    const float* __restrict__ W1, const float* __restrict__ W2,
    const float* __restrict__ D1, const float* __restrict__ D2,
    u16* __restrict__ W1bt, u16* __restrict__ W2bt,
    u16* __restrict__ D1bt, u16* __restrict__ D2bt)
{
  int bid = blockIdx.x;
  int panel = bid >> 9, pb = bid & 511;
  const float* s; u16* d; int R, C, ltc;
  if (panel < 8)       { s = W1 + (size_t)panel * D_DIM * FF_DIM; d = W1bt + (size_t)panel * D_DIM * FF_DIM; R = D_DIM;  C = FF_DIM; ltc = 6; }
  else if (panel < 16) { int e = panel - 8;
                         s = W2 + (size_t)e * FF_DIM * D_DIM;     d = W2bt + (size_t)e * FF_DIM * D_DIM;     R = FF_DIM; C = D_DIM;  ltc = 4; }
  else if (panel == 16){ s = D1; d = D1bt; R = D_DIM;  C = FF_DIM; ltc = 6; }
  else                 { s = D2; d = D2bt; R = FF_DIM; C = D_DIM;  ltc = 4; }
  int tc = pb & ((1 << ltc) - 1), tr = pb >> ltc;    // tr: 128-row tile, tc: 64-col tile

  __shared__ float tile[128][65];
  int t = threadIdx.x;
  #pragma unroll
  for (int p = 0; p < 8; ++p) {
    int r = p * 16 + (t >> 4);
    int c4 = (t & 15) * 4;
    f4 v = *(const f4*)&s[(size_t)(tr * 128 + r) * C + tc * 64 + c4];
    tile[r][c4+0] = v[0]; tile[r][c4+1] = v[1]; tile[r][c4+2] = v[2]; tile[r][c4+3] = v[3];
  }
  __syncthreads();
  #pragma unroll
  for (int q = 0; q < 4; ++q) {
    int oc = q * 16 + (t >> 4);
    int r8 = (t & 15) * 8;
    u16x8 o;
    #pragma unroll
    for (int j = 0; j < 8; ++j) o[j] = f2bf(tile[r8 + j][oc]);
    *(u16x8*)&d[(size_t)(tc * 64 + oc) * R + tr * 128 + r8] = o;
  }
}

// ---- K7/K8: grouped GEMM, m201-style 4-phase/tile, BM=BN=256, BK=64 ----
// r4/r6 verified skeleton: per phase {reads for THIS quadrant; stage EXACTLY
// ONE half-tile (m201-balanced); BAR; lgkm0; setprio+16 MFMA+setprio; BAR}.
// vmcnt(6) once per tile at P4 (certifies tile t+1: in-order retirement of the
// 8 ops staged during tile t-1..t leaves [Bh0,Bh1,Ah0](t+2) = 6 outstanding).
// Stage-region safety: target region's last ds_read drains at the PRIOR
// phase's lgkm0 + barrier (b0@P1->stage P2, b1@P2->stage P3, a0@P1->stage P4,
// a1(prev tile)@P3->stage P1). Mid-phase lgkmcnt(8) in P1 per m201 template.
#define LGKM0() { asm volatile("s_waitcnt lgkmcnt(0)" ::: "memory"); \
                  __builtin_amdgcn_sched_barrier(0); }
#define BAR()   __builtin_amdgcn_s_barrier()

template <int RELU, int GATHER>
__global__ __launch_bounds__(512, 2) void k_gemm8p(
    const u16* __restrict__ Amoe, const u16* __restrict__ Aden,
    const u16* __restrict__ Bexp, const u16* __restrict__ Bden,
    const float* __restrict__ biasexp, const float* __restrict__ biasden,
    u16* __restrict__ Omoe, u16* __restrict__ Oden,
    const int* __restrict__ hdr, const int4* __restrict__ tilemap,
    const int* __restrict__ perm,
    int K, int N, long bexp_stride, int biasexp_stride, int lg2gx)
{
  // bijective XCD-aware swizzle (nwg % 8 == 0 for both launches)
  int gx  = 1 << lg2gx;
  int nwg = gx * gridDim.y;
  int lin = blockIdx.y * gx + blockIdx.x;
  int sw  = (lin & 7) * (nwg >> 3) + (lin >> 3);
  int ct  = sw & (gx - 1);
  int rt  = sw >> lg2gx;
  if (rt >= hdr[18]) return;

  int4 ent = tilemap[rt];
  const u16* B; const float* bias; u16* O;
  if (ent.x == 1) { B = Bden; bias = biasden; O = Oden; }
  else {
    B = Bexp + (size_t)ent.z * bexp_stride;
    bias = biasexp + (size_t)ent.z * biasexp_stride;
    O = Omoe;
  }
  const int row0 = ent.y;

  __shared__ __align__(16) u16 lds[65536];     // 128KB

  const int tid = threadIdx.x;
  const int wid = tid >> 6, l = tid & 63;
  const int wm = wid >> 2, wn = wid & 3;

  // --- staging sources: 4 precomputed row pointers each for A and B ---
  const int srow = wid * 8 + (l >> 3);
  const int skel = ((l & 7) ^ (l >> 3)) * 8;            // swizzled k-elem in [0,64)
  const u16* aSrcP[4];
  const u16* bSrcP[4];
  #pragma unroll
  for (int i = 0; i < 4; ++i) {
    int r = srow + i * 64;
    if (ent.x == 1)      aSrcP[i] = Aden + (size_t)(row0 + r) * K + skel;
    else if (GATHER) {
      int pr = perm[row0 + r]; pr = pr < 0 ? 0 : pr;     // clamp pads to token 0
      aSrcP[i] = Amoe + (size_t)pr * K + skel;
    } else               aSrcP[i] = Amoe + (size_t)(row0 + r) * K + skel;
    bSrcP[i] = B + (size_t)(ct * 256 + r) * K + skel;
  }

  // --- frag-read base pointers; all reads = base + compile-time immediate ---
  const int fr = l & 15, fq = l >> 4;
  const int fx = (l & 7) << 4;                           // row&7 == l&7 for frag rows
  const int cs0 = (fq * 16) ^ fx;
  const int cs1 = (64 + fq * 16) ^ fx;                   // == cs0 ^ 64
  const int brow = (wn & 1) * 64;
  const char* ldsc = (const char*)lds;
  const char* aP0 = ldsc + wm * 16384 + fr * 128 + cs0;
  const char* aP1 = ldsc + wm * 16384 + fr * 128 + cs1;
  const char* bP0 = ldsc + 65536 + (wn >> 1) * 16384 + (brow + fr) * 128 + cs0;
  const char* bP1 = ldsc + 65536 + (wn >> 1) * 16384 + (brow + fr) * 128 + cs1;

  auto STAGE_A = [&](int tt, int h, int bb) {
    u16* dst = &lds[(bb * 2 + h) * 8192 + wid * 512];
    gload16(aSrcP[h * 2]     + tt * 64, dst);
    gload16(aSrcP[h * 2 + 1] + tt * 64, dst + 4096);
  };
  auto STAGE_B = [&](int tt, int h, int bb) {
    u16* dst = &lds[32768 + (bb * 2 + h) * 8192 + wid * 512];
    gload16(bSrcP[h * 2]     + tt * 64, dst);
    gload16(bSrcP[h * 2 + 1] + tt * 64, dst + 4096);
  };

  f32x4 acc[8][4];
  #pragma unroll
  for (int m = 0; m < 8; ++m)
    #pragma unroll
    for (int n = 0; n < 4; ++n) acc[m][n] = (f32x4){0.f, 0.f, 0.f, 0.f};

  bf16x8 a0[4][2], a1[4][2], b0[2][2], b1[2][2];

  #define READ_A0(B_) { _Pragma("unroll") for (int j = 0; j < 4; ++j) { \
      a0[j][0] = *(const bf16x8*)(aP0 + ((B_)*32768 + j*2048)); \
      a0[j][1] = *(const bf16x8*)(aP1 + ((B_)*32768 + j*2048)); } }
  #define READ_A1(B_) { _Pragma("unroll") for (int j = 0; j < 4; ++j) { \
      a1[j][0] = *(const bf16x8*)(aP0 + ((B_)*32768 + 8192 + j*2048)); \
      a1[j][1] = *(const bf16x8*)(aP1 + ((B_)*32768 + 8192 + j*2048)); } }
  #define READ_B0(B_) { _Pragma("unroll") for (int i = 0; i < 2; ++i) { \
      b0[i][0] = *(const bf16x8*)(bP0 + ((B_)*32768 + i*2048)); \
      b0[i][1] = *(const bf16x8*)(bP1 + ((B_)*32768 + i*2048)); } }
  #define READ_B1(B_) { _Pragma("unroll") for (int i = 0; i < 2; ++i) { \
      b1[i][0] = *(const bf16x8*)(bP0 + ((B_)*32768 + 4096 + i*2048)); \
      b1[i][1] = *(const bf16x8*)(bP1 + ((B_)*32768 + 4096 + i*2048)); } }
  #define MFMA_Q(am, bm, mo, no) { __builtin_amdgcn_s_setprio(1); \
    _Pragma("unroll") for (int j = 0; j < 4; ++j) \
      _Pragma("unroll") for (int i = 0; i < 2; ++i) { \
        acc[(mo) + j][(no) + i] = __builtin_amdgcn_mfma_f32_16x16x32_bf16(am[j][0], bm[i][0], acc[(mo) + j][(no) + i], 0, 0, 0); \
        acc[(mo) + j][(no) + i] = __builtin_amdgcn_mfma_f32_16x16x32_bf16(am[j][1], bm[i][1], acc[(mo) + j][(no) + i], 0, 0, 0); } \
    __builtin_amdgcn_s_setprio(0); }

  const int NK = K >> 6;                                 // 16 or 64 (both even)

  // prologue: 7 half-tiles (14 loads); vmcnt(6) retires exactly tile 0's 4
  STAGE_B(0, 0, 0); STAGE_B(0, 1, 0); STAGE_A(0, 0, 0); STAGE_A(0, 1, 0);
  STAGE_B(1, 0, 1); STAGE_B(1, 1, 1); STAGE_A(1, 0, 1);
  asm volatile("s_waitcnt vmcnt(6)" ::: "memory");
  BAR();

  // one K-tile, buf index B_ is a compile-time literal; balanced staging
  #define TILE(B_, t_) { \
    /* P1: reads A-mh0(8)+B-nh0(4); stage Ah1(t+1)@other buf */ \
    READ_A0(B_); READ_B0(B_); \
    if ((t_) + 1 < NK) STAGE_A((t_) + 1, 1, (B_) ^ 1); \
    asm volatile("s_waitcnt lgkmcnt(8)" ::: "memory"); \
    BAR(); LGKM0(); \
    MFMA_Q(a0, b0, 0, 0); \
    BAR(); \
    /* P2: reads B-nh1(4); stage Bh0(t+2)@this buf (b0 drained @P1) */ \
    READ_B1(B_); \
    if ((t_) + 2 < NK) STAGE_B((t_) + 2, 0, (B_)); \
    BAR(); LGKM0(); \
    MFMA_Q(a0, b1, 0, 2); \
    BAR(); \
    /* P3: reads A-mh1(8); stage Bh1(t+2) (b1 drained @P2) */ \
    READ_A1(B_); \
    if ((t_) + 2 < NK) STAGE_B((t_) + 2, 1, (B_)); \
    BAR(); LGKM0(); \
    MFMA_Q(a1, b1, 4, 2); \
    BAR(); \
    /* P4: no reads; stage Ah0(t+2) (a0 drained @P1); vmcnt once per tile */ \
    if ((t_) + 2 < NK) STAGE_A((t_) + 2, 0, (B_)); \
    BAR(); \
    MFMA_Q(a1, b0, 4, 0); \
    if ((t_) < NK - 2) { asm volatile("s_waitcnt vmcnt(6)" ::: "memory"); } \
    else               { asm volatile("s_waitcnt vmcnt(0)" ::: "memory"); } \
    BAR(); \
    __builtin_amdgcn_sched_barrier(0); }

  for (int t = 0; t < NK; t += 2) {
    TILE(0, t);
    TILE(1, t + 1);
  }
  #undef TILE

  // ---- epilogue: per-wave padded LDS-bounce transpose -> u16x8 stores ----
  __syncthreads();
  float bv[4];
  #pragma unroll
  for (int ni = 0; ni < 4; ++ni) bv[ni] = bias[ct * 256 + wn * 64 + ni * 16 + fr];
  float* ep = (float*)((char*)lds + wid * 4608);         // 16 x 68 floats, padded
  const int row16 = l >> 2, cg = l & 3;
  #pragma unroll
  for (int mi = 0; mi < 8; ++mi) {
    #pragma unroll
    for (int ni = 0; ni < 4; ++ni) {
      f32x4 v = acc[mi][ni];
      #pragma unroll
      for (int j = 0; j < 4; ++j) {
        float f = v[j] + bv[ni];
        if (RELU) f = fmaxf(f, 0.f);
        ep[(fq * 4 + j) * 68 + ni * 16 + fr] = f;        // stride 68: 2-way max
      }
    }
    #pragma unroll
    for (int p = 0; p < 2; ++p) {
      f4 r0 = *(f4*)&ep[row16 * 68 + (cg + p * 4) * 8];
      f4 r1 = *(f4*)&ep[row16 * 68 + (cg + p * 4) * 8 + 4];
      u16x8 o;
      o[0]=f2bf(r0[0]); o[1]=f2bf(r0[1]); o[2]=f2bf(r0[2]); o[3]=f2bf(r0[3]);
      o[4]=f2bf(r1[0]); o[5]=f2bf(r1[1]); o[6]=f2bf(r1[2]); o[7]=f2bf(r1[3]);
      int rr = row0 + wm * 128 + mi * 16 + row16;
      int cc = ct * 256 + wn * 64 + (cg + p * 4) * 8;
      *(u16x8*)&O[(size_t)rr * N + cc] = o;
    }
  }
  #undef READ_A0
  #undef READ_A1
  #undef READ_B0
  #undef READ_B1
  #undef MFMA_Q
}

// ---------------- K9: combine ----------------
__global__ __launch_bounds__(128) void k_combine(
    const u16* __restrict__ eo, const u16* __restrict__ dense_o,
    const float4* __restrict__ tok_wf, const int2* __restrict__ tok_slot,
    float* __restrict__ out)
{
  int t = blockIdx.x;
  int c8 = threadIdx.x;
  float4 wf = tok_wf[t];
  int2 sl = tok_slot[t];
  u16x8 a  = *((const u16x8*)(eo + (size_t)sl.x * D_DIM) + c8);
  u16x8 b  = *((const u16x8*)(eo + (size_t)sl.y * D_DIM) + c8);
  u16x8 dn = *((const u16x8*)(dense_o + (size_t)t * D_DIM) + c8);
  float* op = out + (size_t)t * D_DIM + c8 * 8;
  #pragma unroll
  for (int j = 0; j < 8; ++j) {
    float mo = wf.x * bf2f(a[j]) + wf.y * bf2f(b[j]);
    op[j] = wf.z * mo + wf.w * bf2f(dn[j]);
  }
}

// ---------------- launch ----------------
extern "C" void kernel_launch(void* const* d_in, const int* in_sizes, int n_in,
                              void* d_out, int out_size, void* d_ws, size_t ws_size,
                              hipStream_t stream)
{
  const float* x   = (const float*)d_in[0];
  const float* Wr  = (const float*)d_in[1];
  const float* br  = (const float*)d_in[2];
  const float* Wg  = (const float*)d_in[3];
  const float* bg  = (const float*)d_in[4];
  const float* W1  = (const float*)d_in[5];
  const float* b1  = (const float*)d_in[6];
  const float* W2  = (const float*)d_in[7];
  const float* b2  = (const float*)d_in[8];
  const float* D1  = (const float*)d_in[9];
  const float* d1b = (const float*)d_in[10];
  const float* D2  = (const float*)d_in[11];
  const float* d2b = (const float*)d_in[12];
  float* out = (float*)d_out;

  char* base = (char*)d_ws;
  size_t cur = 0;
  auto alloc = [&](size_t b) -> void* {
    void* p = base + cur; cur = (cur + b + 255) & ~(size_t)255; return p;
  };
  int*    hdr      = (int*)   alloc(256 * sizeof(int));
  int4*   tilemap  = (int4*)  alloc((size_t)RT_MAX * sizeof(int4));
  int4*   tok_sel  = (int4*)  alloc((size_t)T_TOK * sizeof(int4));
  float4* tok_wf   = (float4*)alloc((size_t)T_TOK * sizeof(float4));
  int2*   tok_slot = (int2*)  alloc((size_t)T_TOK * sizeof(int2));
  int*    perm     = (int*)   alloc((size_t)SLOT_MAX * sizeof(int));
  u16*    xb       = (u16*)   alloc((size_t)T_TOK * D_DIM * 2);
  u16*    W1bt     = (u16*)   alloc((size_t)E_NUM * D_DIM * FF_DIM * 2);
  u16*    W2bt     = (u16*)   alloc((size_t)E_NUM * D_DIM * FF_DIM * 2);
  u16*    D1bt     = (u16*)   alloc((size_t)D_DIM * FF_DIM * 2);
  u16*    D2bt     = (u16*)   alloc((size_t)D_DIM * FF_DIM * 2);
  u16*    h_moe    = (u16*)   alloc((size_t)SLOT_MAX * FF_DIM * 2);
  u16*    h_dense  = (u16*)   alloc((size_t)T_TOK * FF_DIM * 2);
  u16*    eo       = (u16*)   alloc((size_t)SLOT_MAX * D_DIM * 2);
  u16*    dense_o  = (u16*)   alloc((size_t)T_TOK * D_DIM * 2);
  (void)in_sizes; (void)n_in; (void)out_size; (void)ws_size; // needs ~440 MB of ws

  hipMemsetAsync(hdr, 0, 256 * sizeof(int), stream);
  k_route    <<<T_TOK / 4, 256, 0, stream>>>(x, Wr, br, Wg, bg, hdr, tok_sel, tok_wf, xb);
  k_setup    <<<32, 256, 0, stream>>>(hdr, tilemap, perm, tok_sel, tok_slot);
  k_tcast_all<<<18 * 512, 256, 0, stream>>>(W1, W2, D1, D2, W1bt, W2bt, D1bt, D2bt);

  // GEMM1: gathered tokens x W1 -> relu -> h   (grid 16x104, K=1024, NK=16)
  k_gemm8p<1, 1><<<dim3(FF_DIM / 256, RT_MAX), 512, 0, stream>>>(
      xb, xb, W1bt, D1bt, b1, d1b, h_moe, h_dense, hdr, tilemap, perm,
      D_DIM, FF_DIM, (long)D_DIM * FF_DIM, FF_DIM, 4);
  // GEMM2: h x W2 -> eo   (grid 4x104, K=4096, NK=64)
  k_gemm8p<0, 0><<<dim3(D_DIM / 256, RT_MAX), 512, 0, stream>>>(
      h_moe, h_dense, W2bt, D2bt, b2, d2b, eo, dense_o, hdr, tilemap, perm,
      FF_DIM, D_DIM, (long)D_DIM * FF_DIM, D_DIM, 2);

  k_combine<<<T_TOK, 128, 0, stream>>>(eo, dense_o, tok_wf, tok_slot, out);
}

// Round 11
// 735.644 us; speedup vs baseline: 2.5006x; 1.0303x over previous
//
#include <hip/hip_runtime.h>
#include <stdint.h>

// ---------------- problem constants ----------------
#define T_TOK   8192          // B*S
#define D_DIM   1024
#define FF_DIM  4096
#define E_NUM   8
#define SLOT_MAX 18432        // 16384 + 8*256 (worst-case 256-padded slots)
#define RT_MAX  104           // 72 moe row-tiles + 32 dense row-tiles (256-row tiles)

typedef unsigned int   u32;
typedef unsigned short u16;
typedef __attribute__((ext_vector_type(4))) float  f32x4;
typedef __attribute__((ext_vector_type(4))) float  f4;
typedef __attribute__((ext_vector_type(8))) short  bf16x8;   // 8 bf16 = 4 VGPR
typedef __attribute__((ext_vector_type(8))) unsigned short u16x8;
typedef __attribute__((ext_vector_type(4))) unsigned short u16x4;

__device__ __forceinline__ u16 f2bf(float f) {              // RNE f32->bf16
  u32 u = __builtin_bit_cast(u32, f);
  return (u16)((u + 0x7fffu + ((u >> 16) & 1u)) >> 16);
}
__device__ __forceinline__ float bf2f(u16 h) {
  u32 u = ((u32)h) << 16; return __builtin_bit_cast(float, u);
}

typedef const __attribute__((address_space(1))) u32* gp1_t;
typedef __attribute__((address_space(3))) u32*       lp3_t;
__device__ __forceinline__ void gload16(const u16* g, u16* l) {
  // async global->LDS, 16B/lane, LDS dest = wave-uniform base + lane*16 (linear)
  __builtin_amdgcn_global_load_lds((gp1_t)(const void*)g, (lp3_t)l, 16, 0, 0);
}

// ---- K1: fused prep: route+gate+x-cast (blocks 0..2047) | weight
// cast+transpose (blocks 2048..11263). Heterogeneous mix: route blocks are
// VALU-bound, tcast blocks BW-bound -> co-scheduling fills both pipes.
__global__ __launch_bounds__(256) void k_prep(
    const float* __restrict__ x, const float* __restrict__ Wr, const float* __restrict__ br,
    const float* __restrict__ Wg, const float* __restrict__ bg,
    int* __restrict__ hdr, int4* __restrict__ tok_sel, float4* __restrict__ tok_wf,
    u16* __restrict__ xb,
    const float* __restrict__ W1, const float* __restrict__ W2,
    const float* __restrict__ D1, const float* __restrict__ D2,
    u16* __restrict__ W1bt, u16* __restrict__ W2bt,
    u16* __restrict__ D1bt, u16* __restrict__ D2bt)
{
  __shared__ float tile[128][65];
  if (blockIdx.x < T_TOK / 4) {
    // ---------------- route part: wave per token, 4 d/lane ----------------
    int w = threadIdx.x >> 6, l = threadIdx.x & 63;
    int t = blockIdx.x * 4 + w;
    const float* xt = x + (size_t)t * D_DIM;
    u16* xbt = xb + (size_t)t * D_DIM;
    float p[10];
    #pragma unroll
    for (int i = 0; i < 10; ++i) p[i] = 0.f;
    #pragma unroll
    for (int j = 0; j < 4; ++j) {
      int d0 = j * 256 + l * 4;
      f4 xv = *(const f4*)&xt[d0];
      u16x4 xo; xo[0]=f2bf(xv[0]); xo[1]=f2bf(xv[1]); xo[2]=f2bf(xv[2]); xo[3]=f2bf(xv[3]);
      *(u16x4*)&xbt[d0] = xo;
      f4 wra = *(const f4*)&Wr[d0 * 2];
      f4 wrb = *(const f4*)&Wr[d0 * 2 + 4];
      p[0] += xv[0]*wra[0] + xv[1]*wra[2] + xv[2]*wrb[0] + xv[3]*wrb[2];
      p[1] += xv[0]*wra[1] + xv[1]*wra[3] + xv[2]*wrb[1] + xv[3]*wrb[3];
      #pragma unroll
      for (int i = 0; i < 4; ++i) {
        f4 g0 = *(const f4*)&Wg[(size_t)(d0 + i) * 8];
        f4 g1 = *(const f4*)&Wg[(size_t)(d0 + i) * 8 + 4];
        p[2] += xv[i]*g0[0]; p[3] += xv[i]*g0[1]; p[4] += xv[i]*g0[2]; p[5] += xv[i]*g0[3];
        p[6] += xv[i]*g1[0]; p[7] += xv[i]*g1[1]; p[8] += xv[i]*g1[2]; p[9] += xv[i]*g1[3];
      }
    }
    #pragma unroll
    for (int off = 32; off; off >>= 1) {
      #pragma unroll
      for (int i = 0; i < 10; ++i) p[i] += __shfl_xor(p[i], off, 64);
    }
    if (l == 0) {
      float a0 = p[0] + br[0], a1 = p[1] + br[1];
      float m  = fmaxf(a0, a1);
      float e0 = __expf(a0 - m), e1 = __expf(a1 - m);
      float rs = 1.f / (e0 + e1);
      float rp0 = e0 * rs, rp1 = e1 * rs;
      float g[E_NUM]; float gm = -1e30f;
      #pragma unroll
      for (int e = 0; e < E_NUM; ++e) { g[e] = p[2 + e] + bg[e]; gm = fmaxf(gm, g[e]); }
      int i0 = 0;
      #pragma unroll
      for (int e = 1; e < E_NUM; ++e) if (g[e] > g[i0]) i0 = e;    // earliest max tiebreak
      int i1 = (i0 == 0) ? 1 : 0;
      #pragma unroll
      for (int e = 0; e < E_NUM; ++e) if (e != i0 && g[e] > g[i1]) i1 = e;
      float x0 = __expf(g[i0] - gm), x1 = __expf(g[i1] - gm);
      float s = 1.f / (x0 + x1);
      int r0 = atomicAdd(&hdr[i0], 1);
      int r1 = atomicAdd(&hdr[i1], 1);
      tok_sel[t] = make_int4(i0, r0, i1, r1);
      tok_wf[t]  = make_float4(x0 * s, x1 * s, rp0, rp1);
    }
  } else {
    // ------- tcast part: f32 [R,C] -> bf16 [C,R], 128x64 tiles, 18 panels -------
    int bid = blockIdx.x - T_TOK / 4;
    int panel = bid >> 9, pb = bid & 511;
    const float* s; u16* d; int R, C, ltc;
    if (panel < 8)       { s = W1 + (size_t)panel * D_DIM * FF_DIM; d = W1bt + (size_t)panel * D_DIM * FF_DIM; R = D_DIM;  C = FF_DIM; ltc = 6; }
    else if (panel < 16) { int e = panel - 8;
                           s = W2 + (size_t)e * FF_DIM * D_DIM;     d = W2bt + (size_t)e * FF_DIM * D_DIM;     R = FF_DIM; C = D_DIM;  ltc = 4; }
    else if (panel == 16){ s = D1; d = D1bt; R = D_DIM;  C = FF_DIM; ltc = 6; }
    else                 { s = D2; d = D2bt; R = FF_DIM; C = D_DIM;  ltc = 4; }
    int tc = pb & ((1 << ltc) - 1), tr = pb >> ltc;  // tr: 128-row tile, tc: 64-col tile

    int t = threadIdx.x;
    #pragma unroll
    for (int p = 0; p < 8; ++p) {
      int r = p * 16 + (t >> 4);
      int c4 = (t & 15) * 4;
      f4 v = *(const f4*)&s[(size_t)(tr * 128 + r) * C + tc * 64 + c4];
      tile[r][c4+0] = v[0]; tile[r][c4+1] = v[1]; tile[r][c4+2] = v[2]; tile[r][c4+3] = v[3];
    }
    __syncthreads();
    #pragma unroll
    for (int q = 0; q < 4; ++q) {
      int oc = q * 16 + (t >> 4);
      int r8 = (t & 15) * 8;
      u16x8 o;
      #pragma unroll
      for (int j = 0; j < 8; ++j) o[j] = f2bf(tile[r8 + j][oc]);
      *(u16x8*)&d[(size_t)(tc * 64 + oc) * R + tr * 128 + r8] = o;
    }
  }
}

// ---- K2: setup (offsets + tilemap + pad-init + scatter), 32 blocks ----
// Every block recomputes soff from hdr[0..7]; writes are disjoint:
// tilemap grid-strided, perm init ONLY over pad ranges (never scattered),
// scatter over tokens. No init-then-overwrite race.
__global__ __launch_bounds__(256) void k_setup(
    int* __restrict__ hdr, int4* __restrict__ tilemap, int* __restrict__ perm,
    const int4* __restrict__ tok_sel, int2* __restrict__ tok_slot)
{
  int soff[E_NUM + 1], cnt[E_NUM];
  int acc = 0;
  #pragma unroll
  for (int e = 0; e < E_NUM; ++e) {
    cnt[e] = hdr[e];
    soff[e] = acc;
    acc += (cnt[e] + 255) & ~255;                // pad each expert to 256
  }
  soff[E_NUM] = acc;
  const int gtid = blockIdx.x * 256 + threadIdx.x;
  const int nthr = gridDim.x * 256;
  if (gtid == 0) {
    #pragma unroll
    for (int e = 0; e < E_NUM; ++e) hdr[8 + e] = soff[e];
    hdr[16] = acc;                               // nslots_padded
    hdr[17] = acc >> 8;                          // moe row-tiles (256-row)
    hdr[18] = (acc >> 8) + T_TOK / 256;          // total row-tiles
  }
  int nmoe = acc >> 8;
  for (int rt = gtid; rt < RT_MAX; rt += nthr) {
    int4 ent;
    if (rt < nmoe) {
      int row0 = rt * 256;
      int e = 0;
      while (e < E_NUM - 1 && row0 >= soff[e + 1]) ++e;
      ent = make_int4(0, row0, e, 0);
    } else if (rt < nmoe + T_TOK / 256) {
      ent = make_int4(1, (rt - nmoe) * 256, -1, 0);
    } else {
      ent = make_int4(-1, 0, 0, 0);
    }
    tilemap[rt] = ent;
  }
  #pragma unroll
  for (int e = 0; e < E_NUM; ++e) {              // init pad slots only
    int lo = soff[e] + cnt[e];
    int hi = soff[e + 1];
    for (int s = lo + gtid; s < hi; s += nthr) perm[s] = -1;
  }
  for (int t = gtid; t < T_TOK; t += nthr) {
    int4 s = tok_sel[t];
    int s0 = soff[s.x] + s.y;
    int s1 = soff[s.z] + s.w;
    perm[s0] = t; perm[s1] = t;
    tok_slot[t] = make_int2(s0, s1);
  }
}

// ---- K7/K8: grouped GEMM, m201-style 4-phase/tile, BM=BN=256, BK=64 ----
// r4/r6 verified skeleton: per phase {reads for THIS quadrant; stage EXACTLY
// ONE half-tile (m201-balanced); BAR; lgkm0; setprio+16 MFMA+setprio; BAR}.
// vmcnt(6) once per tile at P4 (certifies tile t+1: in-order retirement of the
// 8 ops staged during tile t-1..t leaves [Bh0,Bh1,Ah0](t+2) = 6 outstanding).
// Stage-region safety: target region's last ds_read drains at the PRIOR
// phase's lgkm0 + barrier (b0@P1->stage P2, b1@P2->stage P3, a0@P1->stage P4,
// a1(prev tile)@P3->stage P1). Mid-phase lgkmcnt(8) in P1 per m201 template.
#define LGKM0() { asm volatile("s_waitcnt lgkmcnt(0)" ::: "memory"); \
                  __builtin_amdgcn_sched_barrier(0); }
#define BAR()   __builtin_amdgcn_s_barrier()

template <int RELU, int GATHER>
__global__ __launch_bounds__(512, 2) void k_gemm8p(
    const u16* __restrict__ Amoe, const u16* __restrict__ Aden,
    const u16* __restrict__ Bexp, const u16* __restrict__ Bden,
    const float* __restrict__ biasexp, const float* __restrict__ biasden,
    u16* __restrict__ Omoe, u16* __restrict__ Oden,
    const int* __restrict__ hdr, const int4* __restrict__ tilemap,
    const int* __restrict__ perm,
    int K, int N, long bexp_stride, int biasexp_stride, int lg2gx)
{
  // bijective XCD-aware swizzle (nwg % 8 == 0 for both launches)
  int gx  = 1 << lg2gx;
  int nwg = gx * gridDim.y;
  int lin = blockIdx.y * gx + blockIdx.x;
  int sw  = (lin & 7) * (nwg >> 3) + (lin >> 3);
  int ct  = sw & (gx - 1);
  int rt  = sw >> lg2gx;
  if (rt >= hdr[18]) return;

  int4 ent = tilemap[rt];
  const u16* B; const float* bias; u16* O;
  if (ent.x == 1) { B = Bden; bias = biasden; O = Oden; }
  else {
    B = Bexp + (size_t)ent.z * bexp_stride;
    bias = biasexp + (size_t)ent.z * biasexp_stride;
    O = Omoe;
  }
  const int row0 = ent.y;

  __shared__ __align__(16) u16 lds[65536];     // 128KB

  const int tid = threadIdx.x;
  const int wid = tid >> 6, l = tid & 63;
  const int wm = wid >> 2, wn = wid & 3;

  // --- staging sources: 4 precomputed row pointers each for A and B ---
  const int srow = wid * 8 + (l >> 3);
  const int skel = ((l & 7) ^ (l >> 3)) * 8;            // swizzled k-elem in [0,64)
  const u16* aSrcP[4];
  const u16* bSrcP[4];
  #pragma unroll
  for (int i = 0; i < 4; ++i) {
    int r = srow + i * 64;
    if (ent.x == 1)      aSrcP[i] = Aden + (size_t)(row0 + r) * K + skel;
    else if (GATHER) {
      int pr = perm[row0 + r]; pr = pr < 0 ? 0 : pr;     // clamp pads to token 0
      aSrcP[i] = Amoe + (size_t)pr * K + skel;
    } else               aSrcP[i] = Amoe + (size_t)(row0 + r) * K + skel;
    bSrcP[i] = B + (size_t)(ct * 256 + r) * K + skel;
  }

  // --- frag-read base pointers; all reads = base + compile-time immediate ---
  const int fr = l & 15, fq = l >> 4;
  const int fx = (l & 7) << 4;                           // row&7 == l&7 for frag rows
  const int cs0 = (fq * 16) ^ fx;
  const int cs1 = (64 + fq * 16) ^ fx;                   // == cs0 ^ 64
  const int brow = (wn & 1) * 64;
  const char* ldsc = (const char*)lds;
  const char* aP0 = ldsc + wm * 16384 + fr * 128 + cs0;
  const char* aP1 = ldsc + wm * 16384 + fr * 128 + cs1;
  const char* bP0 = ldsc + 65536 + (wn >> 1) * 16384 + (brow + fr) * 128 + cs0;
  const char* bP1 = ldsc + 65536 + (wn >> 1) * 16384 + (brow + fr) * 128 + cs1;

  auto STAGE_A = [&](int tt, int h, int bb) {
    u16* dst = &lds[(bb * 2 + h) * 8192 + wid * 512];
    gload16(aSrcP[h * 2]     + tt * 64, dst);
    gload16(aSrcP[h * 2 + 1] + tt * 64, dst + 4096);
  };
  auto STAGE_B = [&](int tt, int h, int bb) {
    u16* dst = &lds[32768 + (bb * 2 + h) * 8192 + wid * 512];
    gload16(bSrcP[h * 2]     + tt * 64, dst);
    gload16(bSrcP[h * 2 + 1] + tt * 64, dst + 4096);
  };

  f32x4 acc[8][4];
  #pragma unroll
  for (int m = 0; m < 8; ++m)
    #pragma unroll
    for (int n = 0; n < 4; ++n) acc[m][n] = (f32x4){0.f, 0.f, 0.f, 0.f};

  bf16x8 a0[4][2], a1[4][2], b0[2][2], b1[2][2];

  #define READ_A0(B_) { _Pragma("unroll") for (int j = 0; j < 4; ++j) { \
      a0[j][0] = *(const bf16x8*)(aP0 + ((B_)*32768 + j*2048)); \
      a0[j][1] = *(const bf16x8*)(aP1 + ((B_)*32768 + j*2048)); } }
  #define READ_A1(B_) { _Pragma("unroll") for (int j = 0; j < 4; ++j) { \
      a1[j][0] = *(const bf16x8*)(aP0 + ((B_)*32768 + 8192 + j*2048)); \
      a1[j][1] = *(const bf16x8*)(aP1 + ((B_)*32768 + 8192 + j*2048)); } }
  #define READ_B0(B_) { _Pragma("unroll") for (int i = 0; i < 2; ++i) { \
      b0[i][0] = *(const bf16x8*)(bP0 + ((B_)*32768 + i*2048)); \
      b0[i][1] = *(const bf16x8*)(bP1 + ((B_)*32768 + i*2048)); } }
  #define READ_B1(B_) { _Pragma("unroll") for (int i = 0; i < 2; ++i) { \
      b1[i][0] = *(const bf16x8*)(bP0 + ((B_)*32768 + 4096 + i*2048)); \
      b1[i][1] = *(const bf16x8*)(bP1 + ((B_)*32768 + 4096 + i*2048)); } }
  #define MFMA_Q(am, bm, mo, no) { __builtin_amdgcn_s_setprio(1); \
    _Pragma("unroll") for (int j = 0; j < 4; ++j) \
      _Pragma("unroll") for (int i = 0; i < 2; ++i) { \
        acc[(mo) + j][(no) + i] = __builtin_amdgcn_mfma_f32_16x16x32_bf16(am[j][0], bm[i][0], acc[(mo) + j][(no) + i], 0, 0, 0); \
        acc[(mo) + j][(no) + i] = __builtin_amdgcn_mfma_f32_16x16x32_bf16(am[j][1], bm[i][1], acc[(mo) + j][(no) + i], 0, 0, 0); } \
    __builtin_amdgcn_s_setprio(0); }

  const int NK = K >> 6;                                 // 16 or 64 (both even)

  // prologue: 7 half-tiles (14 loads); vmcnt(6) retires exactly tile 0's 4
  STAGE_B(0, 0, 0); STAGE_B(0, 1, 0); STAGE_A(0, 0, 0); STAGE_A(0, 1, 0);
  STAGE_B(1, 0, 1); STAGE_B(1, 1, 1); STAGE_A(1, 0, 1);
  asm volatile("s_waitcnt vmcnt(6)" ::: "memory");
  BAR();

  // one K-tile, buf index B_ is a compile-time literal; balanced staging
  #define TILE(B_, t_) { \
    /* P1: reads A-mh0(8)+B-nh0(4); stage Ah1(t+1)@other buf */ \
    READ_A0(B_); READ_B0(B_); \
    if ((t_) + 1 < NK) STAGE_A((t_) + 1, 1, (B_) ^ 1); \
    asm volatile("s_waitcnt lgkmcnt(8)" ::: "memory"); \
    BAR(); LGKM0(); \
    MFMA_Q(a0, b0, 0, 0); \
    BAR(); \
    /* P2: reads B-nh1(4); stage Bh0(t+2)@this buf (b0 drained @P1) */ \
    READ_B1(B_); \
    if ((t_) + 2 < NK) STAGE_B((t_) + 2, 0, (B_)); \
    BAR(); LGKM0(); \
    MFMA_Q(a0, b1, 0, 2); \
    BAR(); \
    /* P3: reads A-mh1(8); stage Bh1(t+2) (b1 drained @P2) */ \
    READ_A1(B_); \
    if ((t_) + 2 < NK) STAGE_B((t_) + 2, 1, (B_)); \
    BAR(); LGKM0(); \
    MFMA_Q(a1, b1, 4, 2); \
    BAR(); \
    /* P4: no reads; stage Ah0(t+2) (a0 drained @P1); vmcnt once per tile */ \
    if ((t_) + 2 < NK) STAGE_A((t_) + 2, 0, (B_)); \
    BAR(); \
    MFMA_Q(a1, b0, 4, 0); \
    if ((t_) < NK - 2) { asm volatile("s_waitcnt vmcnt(6)" ::: "memory"); } \
    else               { asm volatile("s_waitcnt vmcnt(0)" ::: "memory"); } \
    BAR(); \
    __builtin_amdgcn_sched_barrier(0); }

  for (int t = 0; t < NK; t += 2) {
    TILE(0, t);
    TILE(1, t + 1);
  }
  #undef TILE

  // ---- epilogue: per-wave padded LDS-bounce transpose -> u16x8 stores ----
  __syncthreads();
  float bv[4];
  #pragma unroll
  for (int ni = 0; ni < 4; ++ni) bv[ni] = bias[ct * 256 + wn * 64 + ni * 16 + fr];
  float* ep = (float*)((char*)lds + wid * 4608);         // 16 x 68 floats, padded
  const int row16 = l >> 2, cg = l & 3;
  #pragma unroll
  for (int mi = 0; mi < 8; ++mi) {
    #pragma unroll
    for (int ni = 0; ni < 4; ++ni) {
      f32x4 v = acc[mi][ni];
      #pragma unroll
      for (int j = 0; j < 4; ++j) {
        float f = v[j] + bv[ni];
        if (RELU) f = fmaxf(f, 0.f);
        ep[(fq * 4 + j) * 68 + ni * 16 + fr] = f;        // stride 68: 2-way max
      }
    }
    #pragma unroll
    for (int p = 0; p < 2; ++p) {
      f4 r0 = *(f4*)&ep[row16 * 68 + (cg + p * 4) * 8];
      f4 r1 = *(f4*)&ep[row16 * 68 + (cg + p * 4) * 8 + 4];
      u16x8 o;
      o[0]=f2bf(r0[0]); o[1]=f2bf(r0[1]); o[2]=f2bf(r0[2]); o[3]=f2bf(r0[3]);
      o[4]=f2bf(r1[0]); o[5]=f2bf(r1[1]); o[6]=f2bf(r1[2]); o[7]=f2bf(r1[3]);
      int rr = row0 + wm * 128 + mi * 16 + row16;
      int cc = ct * 256 + wn * 64 + (cg + p * 4) * 8;
      *(u16x8*)&O[(size_t)rr * N + cc] = o;
    }
  }
  #undef READ_A0
  #undef READ_A1
  #undef READ_B0
  #undef READ_B1
  #undef MFMA_Q
}

// ---------------- K9: combine (2 tokens per block) ----------------
__global__ __launch_bounds__(256) void k_combine(
    const u16* __restrict__ eo, const u16* __restrict__ dense_o,
    const float4* __restrict__ tok_wf, const int2* __restrict__ tok_slot,
    float* __restrict__ out)
{
  int t = blockIdx.x * 2 + (threadIdx.x >> 7);
  int c8 = threadIdx.x & 127;
  float4 wf = tok_wf[t];
  int2 sl = tok_slot[t];
  u16x8 a  = *((const u16x8*)(eo + (size_t)sl.x * D_DIM) + c8);
  u16x8 b  = *((const u16x8*)(eo + (size_t)sl.y * D_DIM) + c8);
  u16x8 dn = *((const u16x8*)(dense_o + (size_t)t * D_DIM) + c8);
  float* op = out + (size_t)t * D_DIM + c8 * 8;
  #pragma unroll
  for (int j = 0; j < 8; ++j) {
    float mo = wf.x * bf2f(a[j]) + wf.y * bf2f(b[j]);
    op[j] = wf.z * mo + wf.w * bf2f(dn[j]);
  }
}

// ---------------- launch ----------------
extern "C" void kernel_launch(void* const* d_in, const int* in_sizes, int n_in,
                              void* d_out, int out_size, void* d_ws, size_t ws_size,
                              hipStream_t stream)
{
  const float* x   = (const float*)d_in[0];
  const float* Wr  = (const float*)d_in[1];
  const float* br  = (const float*)d_in[2];
  const float* Wg  = (const float*)d_in[3];
  const float* bg  = (const float*)d_in[4];
  const float* W1  = (const float*)d_in[5];
  const float* b1  = (const float*)d_in[6];
  const float* W2  = (const float*)d_in[7];
  const float* b2  = (const float*)d_in[8];
  const float* D1  = (const float*)d_in[9];
  const float* d1b = (const float*)d_in[10];
  const float* D2  = (const float*)d_in[11];
  const float* d2b = (const float*)d_in[12];
  float* out = (float*)d_out;

  char* base = (char*)d_ws;
  size_t cur = 0;
  auto alloc = [&](size_t b) -> void* {
    void* p = base + cur; cur = (cur + b + 255) & ~(size_t)255; return p;
  };
  int*    hdr      = (int*)   alloc(256 * sizeof(int));
  int4*   tilemap  = (int4*)  alloc((size_t)RT_MAX * sizeof(int4));
  int4*   tok_sel  = (int4*)  alloc((size_t)T_TOK * sizeof(int4));
  float4* tok_wf   = (float4*)alloc((size_t)T_TOK * sizeof(float4));
  int2*   tok_slot = (int2*)  alloc((size_t)T_TOK * sizeof(int2));
  int*    perm     = (int*)   alloc((size_t)SLOT_MAX * sizeof(int));
  u16*    xb       = (u16*)   alloc((size_t)T_TOK * D_DIM * 2);
  u16*    W1bt     = (u16*)   alloc((size_t)E_NUM * D_DIM * FF_DIM * 2);
  u16*    W2bt     = (u16*)   alloc((size_t)E_NUM * D_DIM * FF_DIM * 2);
  u16*    D1bt     = (u16*)   alloc((size_t)D_DIM * FF_DIM * 2);
  u16*    D2bt     = (u16*)   alloc((size_t)D_DIM * FF_DIM * 2);
  u16*    h_moe    = (u16*)   alloc((size_t)SLOT_MAX * FF_DIM * 2);
  u16*    h_dense  = (u16*)   alloc((size_t)T_TOK * FF_DIM * 2);
  u16*    eo       = (u16*)   alloc((size_t)SLOT_MAX * D_DIM * 2);
  u16*    dense_o  = (u16*)   alloc((size_t)T_TOK * D_DIM * 2);
  (void)in_sizes; (void)n_in; (void)out_size; (void)ws_size; // needs ~440 MB of ws

  hipMemsetAsync(hdr, 0, 256 * sizeof(int), stream);
  // fused prep: 2048 route blocks + 9216 tcast blocks
  k_prep  <<<T_TOK / 4 + 18 * 512, 256, 0, stream>>>(
      x, Wr, br, Wg, bg, hdr, tok_sel, tok_wf, xb,
      W1, W2, D1, D2, W1bt, W2bt, D1bt, D2bt);
  k_setup <<<32, 256, 0, stream>>>(hdr, tilemap, perm, tok_sel, tok_slot);

  // GEMM1: gathered tokens x W1 -> relu -> h   (grid 16x104, K=1024, NK=16)
  k_gemm8p<1, 1><<<dim3(FF_DIM / 256, RT_MAX), 512, 0, stream>>>(
      xb, xb, W1bt, D1bt, b1, d1b, h_moe, h_dense, hdr, tilemap, perm,
      D_DIM, FF_DIM, (long)D_DIM * FF_DIM, FF_DIM, 4);
  // GEMM2: h x W2 -> eo   (grid 4x104, K=4096, NK=64)
  k_gemm8p<0, 0><<<dim3(D_DIM / 256, RT_MAX), 512, 0, stream>>>(
      h_moe, h_dense, W2bt, D2bt, b2, d2b, eo, dense_o, hdr, tilemap, perm,
      FF_DIM, D_DIM, (long)D_DIM * FF_DIM, D_DIM, 2);

  k_combine<<<T_TOK / 2, 256, 0, stream>>>(eo, dense_o, tok_wf, tok_slot, out);
}

// Round 12
// 734.523 us; speedup vs baseline: 2.5044x; 1.0015x over previous
//
#include <hip/hip_runtime.h>
#include <stdint.h>

// ---------------- problem constants ----------------
#define T_TOK   8192          // B*S
#define D_DIM   1024
#define FF_DIM  4096
#define E_NUM   8
#define SLOT_MAX 18432        // 16384 + 8*256 (worst-case 256-padded slots)
#define RT_MAX  104           // 72 moe row-tiles + 32 dense row-tiles (256-row tiles)

typedef unsigned int   u32;
typedef unsigned short u16;
typedef __attribute__((ext_vector_type(4))) float  f32x4;
typedef __attribute__((ext_vector_type(4))) float  f4;
typedef __attribute__((ext_vector_type(8))) short  bf16x8;   // 8 bf16 = 4 VGPR
typedef __attribute__((ext_vector_type(8))) unsigned short u16x8;
typedef __attribute__((ext_vector_type(4))) unsigned short u16x4;

__device__ __forceinline__ u16 f2bf(float f) {              // RNE f32->bf16
  u32 u = __builtin_bit_cast(u32, f);
  return (u16)((u + 0x7fffu + ((u >> 16) & 1u)) >> 16);
}
__device__ __forceinline__ float bf2f(u16 h) {
  u32 u = ((u32)h) << 16; return __builtin_bit_cast(float, u);
}

typedef const __attribute__((address_space(1))) u32* gp1_t;
typedef __attribute__((address_space(3))) u32*       lp3_t;
__device__ __forceinline__ void gload16(const u16* g, u16* l) {
  // async global->LDS, 16B/lane, LDS dest = wave-uniform base + lane*16 (linear)
  __builtin_amdgcn_global_load_lds((gp1_t)(const void*)g, (lp3_t)l, 16, 0, 0);
}

// ---- K0: transpose router/gate weights (40 KB) so route reads coalesce ----
__global__ __launch_bounds__(256) void k_wgt(
    const float* __restrict__ Wr, const float* __restrict__ Wg,
    float* __restrict__ WrT, float* __restrict__ WgT)
{
  int i = blockIdx.x * 256 + threadIdx.x;           // 0..10239
  if (i < 2 * D_DIM) {
    int e = i >> 10, d = i & (D_DIM - 1);
    WrT[i] = Wr[d * 2 + e];
  } else {
    int ii = i - 2 * D_DIM;
    int e = ii >> 10, d = ii & (D_DIM - 1);
    WgT[ii] = Wg[d * 8 + e];
  }
}

// ---- K1: fused prep: route+gate+x-cast (blocks 0..2047, coalesced WrT/WgT)
// | weight cast+transpose w/ XOR-swizzled LDS (blocks 2048..11263).
__global__ __launch_bounds__(256) void k_prep(
    const float* __restrict__ x, const float* __restrict__ WrT, const float* __restrict__ br,
    const float* __restrict__ WgT, const float* __restrict__ bg,
    int* __restrict__ hdr, int4* __restrict__ tok_sel, float4* __restrict__ tok_wf,
    u16* __restrict__ xb,
    const float* __restrict__ W1, const float* __restrict__ W2,
    const float* __restrict__ D1, const float* __restrict__ D2,
    u16* __restrict__ W1bt, u16* __restrict__ W2bt,
    u16* __restrict__ D1bt, u16* __restrict__ D2bt)
{
  __shared__ float tile[128][65];
  if (blockIdx.x < T_TOK / 4) {
    // ---------------- route part: wave per token, 4 d/lane ----------------
    int w = threadIdx.x >> 6, l = threadIdx.x & 63;
    int t = blockIdx.x * 4 + w;
    const float* xt = x + (size_t)t * D_DIM;
    u16* xbt = xb + (size_t)t * D_DIM;
    float p[10];
    #pragma unroll
    for (int i = 0; i < 10; ++i) p[i] = 0.f;
    #pragma unroll
    for (int j = 0; j < 4; ++j) {
      int d0 = j * 256 + l * 4;
      f4 xv = *(const f4*)&xt[d0];
      u16x4 xo; xo[0]=f2bf(xv[0]); xo[1]=f2bf(xv[1]); xo[2]=f2bf(xv[2]); xo[3]=f2bf(xv[3]);
      *(u16x4*)&xbt[d0] = xo;
      f4 w0 = *(const f4*)&WrT[d0];
      f4 w1 = *(const f4*)&WrT[D_DIM + d0];
      p[0] += xv[0]*w0[0] + xv[1]*w0[1] + xv[2]*w0[2] + xv[3]*w0[3];
      p[1] += xv[0]*w1[0] + xv[1]*w1[1] + xv[2]*w1[2] + xv[3]*w1[3];
      #pragma unroll
      for (int e = 0; e < 8; ++e) {
        f4 g = *(const f4*)&WgT[e * D_DIM + d0];
        p[2 + e] += xv[0]*g[0] + xv[1]*g[1] + xv[2]*g[2] + xv[3]*g[3];
      }
    }
    #pragma unroll
    for (int off = 32; off; off >>= 1) {
      #pragma unroll
      for (int i = 0; i < 10; ++i) p[i] += __shfl_xor(p[i], off, 64);
    }
    if (l == 0) {
      float a0 = p[0] + br[0], a1 = p[1] + br[1];
      float m  = fmaxf(a0, a1);
      float e0 = __expf(a0 - m), e1 = __expf(a1 - m);
      float rs = 1.f / (e0 + e1);
      float rp0 = e0 * rs, rp1 = e1 * rs;
      float g[E_NUM]; float gm = -1e30f;
      #pragma unroll
      for (int e = 0; e < E_NUM; ++e) { g[e] = p[2 + e] + bg[e]; gm = fmaxf(gm, g[e]); }
      int i0 = 0;
      #pragma unroll
      for (int e = 1; e < E_NUM; ++e) if (g[e] > g[i0]) i0 = e;    // earliest max tiebreak
      int i1 = (i0 == 0) ? 1 : 0;
      #pragma unroll
      for (int e = 0; e < E_NUM; ++e) if (e != i0 && g[e] > g[i1]) i1 = e;
      float x0 = __expf(g[i0] - gm), x1 = __expf(g[i1] - gm);
      float s = 1.f / (x0 + x1);
      int r0 = atomicAdd(&hdr[i0], 1);
      int r1 = atomicAdd(&hdr[i1], 1);
      tok_sel[t] = make_int4(i0, r0, i1, r1);
      tok_wf[t]  = make_float4(x0 * s, x1 * s, rp0, rp1);
    }
  } else {
    // -- tcast part: f32 [R,C] -> bf16 [C,R], 128x64 tiles, XOR-swizzled LDS --
    int bid = blockIdx.x - T_TOK / 4;
    int panel = bid >> 9, pb = bid & 511;
    const float* s; u16* d; int R, C, ltc;
    if (panel < 8)       { s = W1 + (size_t)panel * D_DIM * FF_DIM; d = W1bt + (size_t)panel * D_DIM * FF_DIM; R = D_DIM;  C = FF_DIM; ltc = 6; }
    else if (panel < 16) { int e = panel - 8;
                           s = W2 + (size_t)e * FF_DIM * D_DIM;     d = W2bt + (size_t)e * FF_DIM * D_DIM;     R = FF_DIM; C = D_DIM;  ltc = 4; }
    else if (panel == 16){ s = D1; d = D1bt; R = D_DIM;  C = FF_DIM; ltc = 6; }
    else                 { s = D2; d = D2bt; R = FF_DIM; C = D_DIM;  ltc = 4; }
    int tc = pb & ((1 << ltc) - 1), tr = pb >> ltc;  // tr: 128-row tile, tc: 64-col tile

    int t = threadIdx.x;
    #pragma unroll
    for (int p = 0; p < 8; ++p) {
      int r = p * 16 + (t >> 4);
      int c4 = (t & 15) * 4;
      int cx = c4 ^ (((r >> 3) & 7) << 2);          // XOR swizzle (write side)
      f4 v = *(const f4*)&s[(size_t)(tr * 128 + r) * C + tc * 64 + c4];
      tile[r][cx+0] = v[0]; tile[r][cx+1] = v[1]; tile[r][cx+2] = v[2]; tile[r][cx+3] = v[3];
    }
    __syncthreads();
    const int swr = ((t & 15) & 7) << 2;            // == ((r>>3)&7)<<2 for rows r8..r8+7
    #pragma unroll
    for (int q = 0; q < 4; ++q) {
      int oc = q * 16 + (t >> 4);
      int r8 = (t & 15) * 8;
      int ocx = oc ^ swr;                           // XOR swizzle (read side)
      u16x8 o;
      #pragma unroll
      for (int j = 0; j < 8; ++j) o[j] = f2bf(tile[r8 + j][ocx]);
      *(u16x8*)&d[(size_t)(tc * 64 + oc) * R + tr * 128 + r8] = o;
    }
  }
}

// ---- K2: setup (offsets + tilemap + pad-init + scatter), 32 blocks ----
__global__ __launch_bounds__(256) void k_setup(
    int* __restrict__ hdr, int4* __restrict__ tilemap, int* __restrict__ perm,
    const int4* __restrict__ tok_sel, int2* __restrict__ tok_slot)
{
  int soff[E_NUM + 1], cnt[E_NUM];
  int acc = 0;
  #pragma unroll
  for (int e = 0; e < E_NUM; ++e) {
    cnt[e] = hdr[e];
    soff[e] = acc;
    acc += (cnt[e] + 255) & ~255;                // pad each expert to 256
  }
  soff[E_NUM] = acc;
  const int gtid = blockIdx.x * 256 + threadIdx.x;
  const int nthr = gridDim.x * 256;
  if (gtid == 0) {
    #pragma unroll
    for (int e = 0; e < E_NUM; ++e) hdr[8 + e] = soff[e];
    hdr[16] = acc;                               // nslots_padded
    hdr[17] = acc >> 8;                          // moe row-tiles (256-row)
    hdr[18] = (acc >> 8) + T_TOK / 256;          // total row-tiles
  }
  int nmoe = acc >> 8;
  for (int rt = gtid; rt < RT_MAX; rt += nthr) {
    int4 ent;
    if (rt < nmoe) {
      int row0 = rt * 256;
      int e = 0;
      while (e < E_NUM - 1 && row0 >= soff[e + 1]) ++e;
      ent = make_int4(0, row0, e, 0);
    } else if (rt < nmoe + T_TOK / 256) {
      ent = make_int4(1, (rt - nmoe) * 256, -1, 0);
    } else {
      ent = make_int4(-1, 0, 0, 0);
    }
    tilemap[rt] = ent;
  }
  #pragma unroll
  for (int e = 0; e < E_NUM; ++e) {              // init pad slots only
    int lo = soff[e] + cnt[e];
    int hi = soff[e + 1];
    for (int s = lo + gtid; s < hi; s += nthr) perm[s] = -1;
  }
  for (int t = gtid; t < T_TOK; t += nthr) {
    int4 s = tok_sel[t];
    int s0 = soff[s.x] + s.y;
    int s1 = soff[s.z] + s.w;
    perm[s0] = t; perm[s1] = t;
    tok_slot[t] = make_int2(s0, s1);
  }
}

// ---- K7/K8: grouped GEMM, m201-style 4-phase/tile, BM=BN=256, BK=64 ----
// (byte-identical to r10/r11 verified skeleton)
#define LGKM0() { asm volatile("s_waitcnt lgkmcnt(0)" ::: "memory"); \
                  __builtin_amdgcn_sched_barrier(0); }
#define BAR()   __builtin_amdgcn_s_barrier()

template <int RELU, int GATHER>
__global__ __launch_bounds__(512, 2) void k_gemm8p(
    const u16* __restrict__ Amoe, const u16* __restrict__ Aden,
    const u16* __restrict__ Bexp, const u16* __restrict__ Bden,
    const float* __restrict__ biasexp, const float* __restrict__ biasden,
    u16* __restrict__ Omoe, u16* __restrict__ Oden,
    const int* __restrict__ hdr, const int4* __restrict__ tilemap,
    const int* __restrict__ perm,
    int K, int N, long bexp_stride, int biasexp_stride, int lg2gx)
{
  // bijective XCD-aware swizzle (nwg % 8 == 0 for both launches)
  int gx  = 1 << lg2gx;
  int nwg = gx * gridDim.y;
  int lin = blockIdx.y * gx + blockIdx.x;
  int sw  = (lin & 7) * (nwg >> 3) + (lin >> 3);
  int ct  = sw & (gx - 1);
  int rt  = sw >> lg2gx;
  if (rt >= hdr[18]) return;

  int4 ent = tilemap[rt];
  const u16* B; const float* bias; u16* O;
  if (ent.x == 1) { B = Bden; bias = biasden; O = Oden; }
  else {
    B = Bexp + (size_t)ent.z * bexp_stride;
    bias = biasexp + (size_t)ent.z * biasexp_stride;
    O = Omoe;
  }
  const int row0 = ent.y;

  __shared__ __align__(16) u16 lds[65536];     // 128KB

  const int tid = threadIdx.x;
  const int wid = tid >> 6, l = tid & 63;
  const int wm = wid >> 2, wn = wid & 3;

  // --- staging sources: 4 precomputed row pointers each for A and B ---
  const int srow = wid * 8 + (l >> 3);
  const int skel = ((l & 7) ^ (l >> 3)) * 8;            // swizzled k-elem in [0,64)
  const u16* aSrcP[4];
  const u16* bSrcP[4];
  #pragma unroll
  for (int i = 0; i < 4; ++i) {
    int r = srow + i * 64;
    if (ent.x == 1)      aSrcP[i] = Aden + (size_t)(row0 + r) * K + skel;
    else if (GATHER) {
      int pr = perm[row0 + r]; pr = pr < 0 ? 0 : pr;     // clamp pads to token 0
      aSrcP[i] = Amoe + (size_t)pr * K + skel;
    } else               aSrcP[i] = Amoe + (size_t)(row0 + r) * K + skel;
    bSrcP[i] = B + (size_t)(ct * 256 + r) * K + skel;
  }

  // --- frag-read base pointers; all reads = base + compile-time immediate ---
  const int fr = l & 15, fq = l >> 4;
  const int fx = (l & 7) << 4;                           // row&7 == l&7 for frag rows
  const int cs0 = (fq * 16) ^ fx;
  const int cs1 = (64 + fq * 16) ^ fx;                   // == cs0 ^ 64
  const int brow = (wn & 1) * 64;
  const char* ldsc = (const char*)lds;
  const char* aP0 = ldsc + wm * 16384 + fr * 128 + cs0;
  const char* aP1 = ldsc + wm * 16384 + fr * 128 + cs1;
  const char* bP0 = ldsc + 65536 + (wn >> 1) * 16384 + (brow + fr) * 128 + cs0;
  const char* bP1 = ldsc + 65536 + (wn >> 1) * 16384 + (brow + fr) * 128 + cs1;

  auto STAGE_A = [&](int tt, int h, int bb) {
    u16* dst = &lds[(bb * 2 + h) * 8192 + wid * 512];
    gload16(aSrcP[h * 2]     + tt * 64, dst);
    gload16(aSrcP[h * 2 + 1] + tt * 64, dst + 4096);
  };
  auto STAGE_B = [&](int tt, int h, int bb) {
    u16* dst = &lds[32768 + (bb * 2 + h) * 8192 + wid * 512];
    gload16(bSrcP[h * 2]     + tt * 64, dst);
    gload16(bSrcP[h * 2 + 1] + tt * 64, dst + 4096);
  };

  f32x4 acc[8][4];
  #pragma unroll
  for (int m = 0; m < 8; ++m)
    #pragma unroll
    for (int n = 0; n < 4; ++n) acc[m][n] = (f32x4){0.f, 0.f, 0.f, 0.f};

  bf16x8 a0[4][2], a1[4][2], b0[2][2], b1[2][2];

  #define READ_A0(B_) { _Pragma("unroll") for (int j = 0; j < 4; ++j) { \
      a0[j][0] = *(const bf16x8*)(aP0 + ((B_)*32768 + j*2048)); \
      a0[j][1] = *(const bf16x8*)(aP1 + ((B_)*32768 + j*2048)); } }
  #define READ_A1(B_) { _Pragma("unroll") for (int j = 0; j < 4; ++j) { \
      a1[j][0] = *(const bf16x8*)(aP0 + ((B_)*32768 + 8192 + j*2048)); \
      a1[j][1] = *(const bf16x8*)(aP1 + ((B_)*32768 + 8192 + j*2048)); } }
  #define READ_B0(B_) { _Pragma("unroll") for (int i = 0; i < 2; ++i) { \
      b0[i][0] = *(const bf16x8*)(bP0 + ((B_)*32768 + i*2048)); \
      b0[i][1] = *(const bf16x8*)(bP1 + ((B_)*32768 + i*2048)); } }
  #define READ_B1(B_) { _Pragma("unroll") for (int i = 0; i < 2; ++i) { \
      b1[i][0] = *(const bf16x8*)(bP0 + ((B_)*32768 + 4096 + i*2048)); \
      b1[i][1] = *(const bf16x8*)(bP1 + ((B_)*32768 + 4096 + i*2048)); } }
  #define MFMA_Q(am, bm, mo, no) { __builtin_amdgcn_s_setprio(1); \
    _Pragma("unroll") for (int j = 0; j < 4; ++j) \
      _Pragma("unroll") for (int i = 0; i < 2; ++i) { \
        acc[(mo) + j][(no) + i] = __builtin_amdgcn_mfma_f32_16x16x32_bf16(am[j][0], bm[i][0], acc[(mo) + j][(no) + i], 0, 0, 0); \
        acc[(mo) + j][(no) + i] = __builtin_amdgcn_mfma_f32_16x16x32_bf16(am[j][1], bm[i][1], acc[(mo) + j][(no) + i], 0, 0, 0); } \
    __builtin_amdgcn_s_setprio(0); }

  const int NK = K >> 6;                                 // 16 or 64 (both even)

  // prologue: 7 half-tiles (14 loads); vmcnt(6) retires exactly tile 0's 4
  STAGE_B(0, 0, 0); STAGE_B(0, 1, 0); STAGE_A(0, 0, 0); STAGE_A(0, 1, 0);
  STAGE_B(1, 0, 1); STAGE_B(1, 1, 1); STAGE_A(1, 0, 1);
  asm volatile("s_waitcnt vmcnt(6)" ::: "memory");
  BAR();

  // one K-tile, buf index B_ is a compile-time literal; balanced staging
  #define TILE(B_, t_) { \
    /* P1: reads A-mh0(8)+B-nh0(4); stage Ah1(t+1)@other buf */ \
    READ_A0(B_); READ_B0(B_); \
    if ((t_) + 1 < NK) STAGE_A((t_) + 1, 1, (B_) ^ 1); \
    asm volatile("s_waitcnt lgkmcnt(8)" ::: "memory"); \
    BAR(); LGKM0(); \
    MFMA_Q(a0, b0, 0, 0); \
    BAR(); \
    /* P2: reads B-nh1(4); stage Bh0(t+2)@this buf (b0 drained @P1) */ \
    READ_B1(B_); \
    if ((t_) + 2 < NK) STAGE_B((t_) + 2, 0, (B_)); \
    BAR(); LGKM0(); \
    MFMA_Q(a0, b1, 0, 2); \
    BAR(); \
    /* P3: reads A-mh1(8); stage Bh1(t+2) (b1 drained @P2) */ \
    READ_A1(B_); \
    if ((t_) + 2 < NK) STAGE_B((t_) + 2, 1, (B_)); \
    BAR(); LGKM0(); \
    MFMA_Q(a1, b1, 4, 2); \
    BAR(); \
    /* P4: no reads; stage Ah0(t+2) (a0 drained @P1); vmcnt once per tile */ \
    if ((t_) + 2 < NK) STAGE_A((t_) + 2, 0, (B_)); \
    BAR(); \
    MFMA_Q(a1, b0, 4, 0); \
    if ((t_) < NK - 2) { asm volatile("s_waitcnt vmcnt(6)" ::: "memory"); } \
    else               { asm volatile("s_waitcnt vmcnt(0)" ::: "memory"); } \
    BAR(); \
    __builtin_amdgcn_sched_barrier(0); }

  for (int t = 0; t < NK; t += 2) {
    TILE(0, t);
    TILE(1, t + 1);
  }
  #undef TILE

  // ---- epilogue: per-wave padded LDS-bounce transpose -> u16x8 stores ----
  __syncthreads();
  float bv[4];
  #pragma unroll
  for (int ni = 0; ni < 4; ++ni) bv[ni] = bias[ct * 256 + wn * 64 + ni * 16 + fr];
  float* ep = (float*)((char*)lds + wid * 4608);         // 16 x 68 floats, padded
  const int row16 = l >> 2, cg = l & 3;
  #pragma unroll
  for (int mi = 0; mi < 8; ++mi) {
    #pragma unroll
    for (int ni = 0; ni < 4; ++ni) {
      f32x4 v = acc[mi][ni];
      #pragma unroll
      for (int j = 0; j < 4; ++j) {
        float f = v[j] + bv[ni];
        if (RELU) f = fmaxf(f, 0.f);
        ep[(fq * 4 + j) * 68 + ni * 16 + fr] = f;        // stride 68: 2-way max
      }
    }
    #pragma unroll
    for (int p = 0; p < 2; ++p) {
      f4 r0 = *(f4*)&ep[row16 * 68 + (cg + p * 4) * 8];
      f4 r1 = *(f4*)&ep[row16 * 68 + (cg + p * 4) * 8 + 4];
      u16x8 o;
      o[0]=f2bf(r0[0]); o[1]=f2bf(r0[1]); o[2]=f2bf(r0[2]); o[3]=f2bf(r0[3]);
      o[4]=f2bf(r1[0]); o[5]=f2bf(r1[1]); o[6]=f2bf(r1[2]); o[7]=f2bf(r1[3]);
      int rr = row0 + wm * 128 + mi * 16 + row16;
      int cc = ct * 256 + wn * 64 + (cg + p * 4) * 8;
      *(u16x8*)&O[(size_t)rr * N + cc] = o;
    }
  }
  #undef READ_A0
  #undef READ_A1
  #undef READ_B0
  #undef READ_B1
  #undef MFMA_Q
}

// ---------------- K9: combine (2 tokens per block) ----------------
__global__ __launch_bounds__(256) void k_combine(
    const u16* __restrict__ eo, const u16* __restrict__ dense_o,
    const float4* __restrict__ tok_wf, const int2* __restrict__ tok_slot,
    float* __restrict__ out)
{
  int t = blockIdx.x * 2 + (threadIdx.x >> 7);
  int c8 = threadIdx.x & 127;
  float4 wf = tok_wf[t];
  int2 sl = tok_slot[t];
  u16x8 a  = *((const u16x8*)(eo + (size_t)sl.x * D_DIM) + c8);
  u16x8 b  = *((const u16x8*)(eo + (size_t)sl.y * D_DIM) + c8);
  u16x8 dn = *((const u16x8*)(dense_o + (size_t)t * D_DIM) + c8);
  float* op = out + (size_t)t * D_DIM + c8 * 8;
  #pragma unroll
  for (int j = 0; j < 8; ++j) {
    float mo = wf.x * bf2f(a[j]) + wf.y * bf2f(b[j]);
    op[j] = wf.z * mo + wf.w * bf2f(dn[j]);
  }
}

// ---------------- launch ----------------
extern "C" void kernel_launch(void* const* d_in, const int* in_sizes, int n_in,
                              void* d_out, int out_size, void* d_ws, size_t ws_size,
                              hipStream_t stream)
{
  const float* x   = (const float*)d_in[0];
  const float* Wr  = (const float*)d_in[1];
  const float* br  = (const float*)d_in[2];
  const float* Wg  = (const float*)d_in[3];
  const float* bg  = (const float*)d_in[4];
  const float* W1  = (const float*)d_in[5];
  const float* b1  = (const float*)d_in[6];
  const float* W2  = (const float*)d_in[7];
  const float* b2  = (const float*)d_in[8];
  const float* D1  = (const float*)d_in[9];
  const float* d1b = (const float*)d_in[10];
  const float* D2  = (const float*)d_in[11];
  const float* d2b = (const float*)d_in[12];
  float* out = (float*)d_out;

  char* base = (char*)d_ws;
  size_t cur = 0;
  auto alloc = [&](size_t b) -> void* {
    void* p = base + cur; cur = (cur + b + 255) & ~(size_t)255; return p;
  };
  int*    hdr      = (int*)   alloc(256 * sizeof(int));
  int4*   tilemap  = (int4*)  alloc((size_t)RT_MAX * sizeof(int4));
  int4*   tok_sel  = (int4*)  alloc((size_t)T_TOK * sizeof(int4));
  float4* tok_wf   = (float4*)alloc((size_t)T_TOK * sizeof(float4));
  int2*   tok_slot = (int2*)  alloc((size_t)T_TOK * sizeof(int2));
  int*    perm     = (int*)   alloc((size_t)SLOT_MAX * sizeof(int));
  float*  WrT      = (float*) alloc((size_t)2 * D_DIM * sizeof(float));
  float*  WgT      = (float*) alloc((size_t)E_NUM * D_DIM * sizeof(float));
  u16*    xb       = (u16*)   alloc((size_t)T_TOK * D_DIM * 2);
  u16*    W1bt     = (u16*)   alloc((size_t)E_NUM * D_DIM * FF_DIM * 2);
  u16*    W2bt     = (u16*)   alloc((size_t)E_NUM * D_DIM * FF_DIM * 2);
  u16*    D1bt     = (u16*)   alloc((size_t)D_DIM * FF_DIM * 2);
  u16*    D2bt     = (u16*)   alloc((size_t)D_DIM * FF_DIM * 2);
  u16*    h_moe    = (u16*)   alloc((size_t)SLOT_MAX * FF_DIM * 2);
  u16*    h_dense  = (u16*)   alloc((size_t)T_TOK * FF_DIM * 2);
  u16*    eo       = (u16*)   alloc((size_t)SLOT_MAX * D_DIM * 2);
  u16*    dense_o  = (u16*)   alloc((size_t)T_TOK * D_DIM * 2);
  (void)in_sizes; (void)n_in; (void)out_size; (void)ws_size; // needs ~440 MB of ws

  hipMemsetAsync(hdr, 0, 256 * sizeof(int), stream);
  k_wgt   <<<40, 256, 0, stream>>>(Wr, Wg, WrT, WgT);
  // fused prep: 2048 route blocks + 9216 tcast blocks
  k_prep  <<<T_TOK / 4 + 18 * 512, 256, 0, stream>>>(
      x, WrT, br, WgT, bg, hdr, tok_sel, tok_wf, xb,
      W1, W2, D1, D2, W1bt, W2bt, D1bt, D2bt);
  k_setup <<<32, 256, 0, stream>>>(hdr, tilemap, perm, tok_sel, tok_slot);

  // GEMM1: gathered tokens x W1 -> relu -> h   (grid 16x104, K=1024, NK=16)
  k_gemm8p<1, 1><<<dim3(FF_DIM / 256, RT_MAX), 512, 0, stream>>>(
      xb, xb, W1bt, D1bt, b1, d1b, h_moe, h_dense, hdr, tilemap, perm,
      D_DIM, FF_DIM, (long)D_DIM * FF_DIM, FF_DIM, 4);
  // GEMM2: h x W2 -> eo   (grid 4x104, K=4096, NK=64)
  k_gemm8p<0, 0><<<dim3(D_DIM / 256, RT_MAX), 512, 0, stream>>>(
      h_moe, h_dense, W2bt, D2bt, b2, d2b, eo, dense_o, hdr, tilemap, perm,
      FF_DIM, D_DIM, (long)D_DIM * FF_DIM, D_DIM, 2);

  k_combine<<<T_TOK / 2, 256, 0, stream>>>(eo, dense_o, tok_wf, tok_slot, out);
}